// Round 1
// baseline (4494.044 us; speedup 1.0000x reference)
//
#include <hip/hip_runtime.h>

#define LL 13
#define BB 32
#define NN 512
#define HH 768
#define MM 384
#define EE 768
#define BN (BB*NN)   // 16384

// ---------------- workspace layout (floats) ----------------
constexpr size_t SZ_DOWN = (size_t)LL*BN*MM;        // 81,788,928
constexpr size_t SZ_CW   = (size_t)BB*NN*NN;        //  8,388,608
constexpr size_t SZ_MSUM = (size_t)BB*NN*MM;        //  6,291,456
constexpr size_t OFF_DOWN = 0;
constexpr size_t OFF_CW   = OFF_DOWN + SZ_DOWN;
constexpr size_t OFF_MSUM = OFF_CW   + SZ_CW;
constexpr size_t OFF_TMP  = OFF_MSUM + SZ_MSUM;
constexpr size_t OFF_TAGG = OFF_TMP  + SZ_MSUM;
constexpr size_t OFF_ANCH = OFF_TAGG + (size_t)12*BB*MM;
constexpr size_t OFF_CONF = OFF_ANCH + (size_t)BB*MM;
constexpr size_t OFF_RSUM = OFF_CONF + (size_t)BB*12;

// ---------------- fp32 tiled GEMM core: 64x64 tile, K-tile 16, 256 thr, 4x4 micro ----------------
// A is always row-major with the reduction dim contiguous (lda = row stride).
// B: BT=false -> B row-major, rows = reduction dim (normal GEMM B).
//    BT=true  -> B row-major with reduction contiguous (computes A @ B^T).
template<bool BT>
__device__ __forceinline__ void gemm_tile(const float* __restrict__ A, int lda,
                                          const float* __restrict__ Bm, int ldb,
                                          int K, int row0, int col0,
                                          float acc[4][4])
{
    __shared__ float As[16][68];   // As[k][row]
    __shared__ float Bs[16][72];   // Bs[k][col]
    const int tid = threadIdx.x;
    const int tx = tid & 15, ty = tid >> 4;

    for (int k0 = 0; k0 < K; k0 += 16) {
        {   // A tile: 64 rows x 16 k, transpose on store
            int row = tid >> 2;
            int kq  = (tid & 3) * 4;
            float4 v = *(const float4*)(A + (size_t)(row0 + row)*lda + k0 + kq);
            As[kq+0][row] = v.x; As[kq+1][row] = v.y;
            As[kq+2][row] = v.z; As[kq+3][row] = v.w;
        }
        if (BT) {   // B tile: 64 cols x 16 k (reduction contiguous), transpose on store
            int col = tid >> 2;
            int kq  = (tid & 3) * 4;
            float4 v = *(const float4*)(Bm + (size_t)(col0 + col)*ldb + k0 + kq);
            Bs[kq+0][col] = v.x; Bs[kq+1][col] = v.y;
            Bs[kq+2][col] = v.z; Bs[kq+3][col] = v.w;
        } else {    // B tile: 16 k-rows x 64 cols, direct float4 store
            int kr = tid >> 4;
            int c4 = (tid & 15) * 4;
            float4 v = *(const float4*)(Bm + (size_t)(k0 + kr)*ldb + col0 + c4);
            *(float4*)&Bs[kr][c4] = v;
        }
        __syncthreads();
        #pragma unroll
        for (int kk = 0; kk < 16; ++kk) {
            float4 av = *(const float4*)&As[kk][ty*4];
            float4 bv = *(const float4*)&Bs[kk][tx*4];
            float a[4] = {av.x, av.y, av.z, av.w};
            float b[4] = {bv.x, bv.y, bv.z, bv.w};
            #pragma unroll
            for (int i = 0; i < 4; ++i)
                #pragma unroll
                for (int j = 0; j < 4; ++j)
                    acc[i][j] = fmaf(a[i], b[j], acc[i][j]);
        }
        __syncthreads();
    }
}

// ---------------- K1: down-projection GEMM (pre-LN, +bias) ----------------
__global__ __launch_bounds__(256) void k_down(const float* __restrict__ X,
                                              const float* __restrict__ Wd,
                                              const float* __restrict__ bd,
                                              float* __restrict__ out)
{
    const int l  = blockIdx.z;
    const int row0 = blockIdx.x * 64;
    const int col0 = blockIdx.y * 64;
    const float* A = X  + (size_t)l*BN*HH;
    const float* Bm = Wd + (size_t)l*HH*MM;
    float acc[4][4] = {};
    gemm_tile<false>(A, HH, Bm, MM, HH, row0, col0, acc);

    const int tx = threadIdx.x & 15, ty = threadIdx.x >> 4;
    float* C = out + (size_t)l*BN*MM;
    #pragma unroll
    for (int i = 0; i < 4; ++i) {
        int r = row0 + ty*4 + i;
        int c = col0 + tx*4;
        float4 bias = *(const float4*)&bd[l*MM + c];
        float4 st = { acc[i][0]+bias.x, acc[i][1]+bias.y, acc[i][2]+bias.z, acc[i][3]+bias.w };
        *(float4*)&C[(size_t)r*MM + c] = st;
    }
}

// ---------------- K2: LayerNorm in place over last dim (M=384), one wave per row ----------------
__global__ __launch_bounds__(256) void k_ln(float* __restrict__ down,
                                            const float* __restrict__ g,
                                            const float* __restrict__ beta)
{
    const int row  = blockIdx.x*4 + (threadIdx.x >> 6);
    const int lane = threadIdx.x & 63;
    const int l = row / BN;
    float* p = down + (size_t)row*MM;
    float v[6];
    float s = 0.f, s2 = 0.f;
    #pragma unroll
    for (int t = 0; t < 6; ++t) {
        v[t] = p[lane + t*64];
        s  += v[t];
        s2 += v[t]*v[t];
    }
    #pragma unroll
    for (int off = 32; off > 0; off >>= 1) {
        s  += __shfl_xor(s,  off);
        s2 += __shfl_xor(s2, off);
    }
    float mu  = s  * (1.f/MM);
    float var = s2 * (1.f/MM) - mu*mu;
    float inv = rsqrtf(var + 1e-5f);
    #pragma unroll
    for (int t = 0; t < 6; ++t) {
        int m = lane + t*64;
        p[m] = (v[t]-mu)*inv * g[l*MM + m] + beta[l*MM + m];
    }
}

// ---------------- K3: masked means -> t_agg (l<12), anchor (l==12) ----------------
__global__ __launch_bounds__(384) void k_agg(const float* __restrict__ down,
                                             const int* __restrict__ lengths,
                                             float* __restrict__ t_agg,
                                             float* __restrict__ anchor)
{
    const int b = blockIdx.x;
    const int l = blockIdx.y;
    const int m = threadIdx.x;
    const int len = lengths[b];
    const float* p = down + ((size_t)l*BB + b)*NN*MM;
    float s = 0.f;
    for (int n = 0; n < len; ++n) s += p[(size_t)n*MM + m];
    s /= (float)len;
    if (l == 12) anchor[b*MM + m] = s;
    else         t_agg[((size_t)l*BB + b)*MM + m] = s;
}

// ---------------- K4: logits + softmax over l -> conf[b][l] ----------------
__global__ __launch_bounds__(64) void k_conf(const float* __restrict__ anchor,
                                             const float* __restrict__ t_agg,
                                             const float* __restrict__ Wg,
                                             const float* __restrict__ bg,
                                             float* __restrict__ conf)
{
    const int b = blockIdx.x;
    const int lane = threadIdx.x;
    float lg[12];
    #pragma unroll
    for (int l = 0; l < 12; ++l) {
        float s = 0.f;
        #pragma unroll
        for (int t = 0; t < 6; ++t) {
            int m = lane + t*64;
            s += anchor[b*MM + m] * t_agg[((size_t)l*BB + b)*MM + m] * Wg[m];
        }
        #pragma unroll
        for (int off = 32; off > 0; off >>= 1) s += __shfl_xor(s, off);
        lg[l] = s + bg[0];
    }
    float mx = lg[0];
    #pragma unroll
    for (int l = 1; l < 12; ++l) mx = fmaxf(mx, lg[l]);
    float den = 0.f, e[12];
    #pragma unroll
    for (int l = 0; l < 12; ++l) { e[l] = expf(lg[l]-mx); den += e[l]; }
    if (lane == 0) {
        #pragma unroll
        for (int l = 0; l < 12; ++l) conf[b*12 + l] = e[l]/den;
    }
}

// ---------------- K5: msum init with identity term: sum_l conf[b][l]*down[l][b][n][m] ----------------
__global__ __launch_bounds__(256) void k_msum_init(const float* __restrict__ down,
                                                   const float* __restrict__ conf,
                                                   float* __restrict__ msum)
{
    size_t i = (size_t)blockIdx.x*256 + threadIdx.x;   // over B*N*M
    int b = (int)(i / ((size_t)NN*MM));
    float s = 0.f;
    #pragma unroll
    for (int l = 0; l < 12; ++l)
        s += conf[b*12 + l] * down[(size_t)l*BN*MM + i];
    msum[i] = s;
}

// ---------------- K6: S = anchor_feat @ targets^T, relu, mask over k ----------------
__global__ __launch_bounds__(256) void k_s(const float* __restrict__ down,
                                           const int* __restrict__ lengths,
                                           float* __restrict__ cw, int l)
{
    const int b = blockIdx.z;
    const int row0 = blockIdx.x * 64;
    const int col0 = blockIdx.y * 64;
    const float* A  = down + ((size_t)12*BB + b)*NN*MM;  // anchor_feat[b]
    const float* Bm = down + ((size_t)l*BB  + b)*NN*MM;  // targets[l][b]
    float acc[4][4] = {};
    gemm_tile<true>(A, MM, Bm, MM, MM, row0, col0, acc);

    const int tx = threadIdx.x & 15, ty = threadIdx.x >> 4;
    const int len = lengths[b];
    float* C = cw + (size_t)b*NN*NN;
    #pragma unroll
    for (int i = 0; i < 4; ++i) {
        int n = row0 + ty*4 + i;
        int k = col0 + tx*4;
        float4 st;
        st.x = (k+0 < len) ? fmaxf(acc[i][0], 0.f) : 0.f;
        st.y = (k+1 < len) ? fmaxf(acc[i][1], 0.f) : 0.f;
        st.z = (k+2 < len) ? fmaxf(acc[i][2], 0.f) : 0.f;
        st.w = (k+3 < len) ? fmaxf(acc[i][3], 0.f) : 0.f;
        *(float4*)&C[(size_t)n*NN + k] = st;
    }
}

// ---------------- K6b: row sums of cw ----------------
__global__ __launch_bounds__(256) void k_rowsum(const float* __restrict__ cw,
                                                float* __restrict__ rowsum)
{
    const int row  = blockIdx.x*4 + (threadIdx.x >> 6);
    const int lane = threadIdx.x & 63;
    const float* p = cw + (size_t)row*NN;
    float s = 0.f;
    #pragma unroll
    for (int t = 0; t < 8; ++t) s += p[lane + t*64];
    #pragma unroll
    for (int off = 32; off > 0; off >>= 1) s += __shfl_xor(s, off);
    if (lane == 0) rowsum[row] = s;
}

// ---------------- K7: msum += conf/(rowsum+eps) * (cw @ targets) ----------------
__global__ __launch_bounds__(256) void k_merge(const float* __restrict__ cw,
                                               const float* __restrict__ down,
                                               const float* __restrict__ rowsum,
                                               const float* __restrict__ conf,
                                               float* __restrict__ msum, int l)
{
    const int b = blockIdx.z;
    const int row0 = blockIdx.x * 64;
    const int col0 = blockIdx.y * 64;
    const float* A  = cw   + (size_t)b*NN*NN;
    const float* Bm = down + ((size_t)l*BB + b)*NN*MM;
    float acc[4][4] = {};
    gemm_tile<false>(A, NN, Bm, MM, NN, row0, col0, acc);

    const int tx = threadIdx.x & 15, ty = threadIdx.x >> 4;
    const float c = conf[b*12 + l];
    #pragma unroll
    for (int i = 0; i < 4; ++i) {
        int n = row0 + ty*4 + i;
        float sc = c / (rowsum[b*NN + n] + 1e-8f);
        int m = col0 + tx*4;
        float* p = &msum[((size_t)b*NN + n)*MM + m];
        float4 cur = *(float4*)p;
        cur.x += acc[i][0]*sc; cur.y += acc[i][1]*sc;
        cur.z += acc[i][2]*sc; cur.w += acc[i][3]*sc;
        *(float4*)p = cur;
    }
}

// ---------------- K8: proj GEMM (+bias) ----------------
__global__ __launch_bounds__(256) void k_proj(const float* __restrict__ msum,
                                              const float* __restrict__ Wp,
                                              const float* __restrict__ bp,
                                              float* __restrict__ tmp)
{
    const int row0 = blockIdx.x * 64;
    const int col0 = blockIdx.y * 64;
    float acc[4][4] = {};
    gemm_tile<false>(msum, MM, Wp, MM, MM, row0, col0, acc);
    const int tx = threadIdx.x & 15, ty = threadIdx.x >> 4;
    #pragma unroll
    for (int i = 0; i < 4; ++i) {
        int r = row0 + ty*4 + i;
        int c = col0 + tx*4;
        float4 bias = *(const float4*)&bp[c];
        float4 st = { acc[i][0]+bias.x, acc[i][1]+bias.y, acc[i][2]+bias.z, acc[i][3]+bias.w };
        *(float4*)&tmp[(size_t)r*MM + c] = st;
    }
}

// ---------------- K9: R = relu(anchor_feat + LN(tmp)) in place ----------------
__global__ __launch_bounds__(256) void k_ln2(float* __restrict__ tmp,
                                             const float* __restrict__ down,
                                             const float* __restrict__ g,
                                             const float* __restrict__ beta)
{
    const int row  = blockIdx.x*4 + (threadIdx.x >> 6);
    const int lane = threadIdx.x & 63;
    float* p = tmp + (size_t)row*MM;
    const float* af = down + (size_t)12*BN*MM + (size_t)row*MM;
    float v[6];
    float s = 0.f, s2 = 0.f;
    #pragma unroll
    for (int t = 0; t < 6; ++t) {
        v[t] = p[lane + t*64];
        s  += v[t];
        s2 += v[t]*v[t];
    }
    #pragma unroll
    for (int off = 32; off > 0; off >>= 1) {
        s  += __shfl_xor(s,  off);
        s2 += __shfl_xor(s2, off);
    }
    float mu  = s  * (1.f/MM);
    float var = s2 * (1.f/MM) - mu*mu;
    float inv = rsqrtf(var + 1e-5f);
    #pragma unroll
    for (int t = 0; t < 6; ++t) {
        int m = lane + t*64;
        float o = af[m] + (v[t]-mu)*inv * g[m] + beta[m];
        p[m] = fmaxf(o, 0.f);
    }
}

// ---------------- K10: final up GEMM (+bias) -> d_out ----------------
__global__ __launch_bounds__(256) void k_up(const float* __restrict__ R,
                                            const float* __restrict__ Wu,
                                            const float* __restrict__ bu,
                                            float* __restrict__ Y)
{
    const int row0 = blockIdx.x * 64;
    const int col0 = blockIdx.y * 64;
    float acc[4][4] = {};
    gemm_tile<false>(R, MM, Wu, EE, MM, row0, col0, acc);
    const int tx = threadIdx.x & 15, ty = threadIdx.x >> 4;
    #pragma unroll
    for (int i = 0; i < 4; ++i) {
        int r = row0 + ty*4 + i;
        int c = col0 + tx*4;
        float4 bias = *(const float4*)&bu[c];
        float4 st = { acc[i][0]+bias.x, acc[i][1]+bias.y, acc[i][2]+bias.z, acc[i][3]+bias.w };
        *(float4*)&Y[(size_t)r*EE + c] = st;
    }
}

// ---------------- K11: lengths -> d_out tail (as float values) ----------------
__global__ void k_len(const int* __restrict__ lengths, float* __restrict__ out)
{
    if (threadIdx.x < BB)
        out[(size_t)BB*NN*EE + threadIdx.x] = (float)lengths[threadIdx.x];
}

extern "C" void kernel_launch(void* const* d_in, const int* in_sizes, int n_in,
                              void* d_out, int out_size, void* d_ws, size_t ws_size,
                              hipStream_t stream)
{
    const float* X    = (const float*)d_in[0];
    const int*   len  = (const int*)  d_in[1];
    const float* Wd   = (const float*)d_in[2];
    const float* bd   = (const float*)d_in[3];
    const float* gd   = (const float*)d_in[4];
    const float* betd = (const float*)d_in[5];
    const float* Wp   = (const float*)d_in[6];
    const float* bp   = (const float*)d_in[7];
    const float* gp   = (const float*)d_in[8];
    const float* betp = (const float*)d_in[9];
    const float* Wu   = (const float*)d_in[10];
    const float* bu   = (const float*)d_in[11];
    const float* Wg   = (const float*)d_in[12];
    const float* bg   = (const float*)d_in[13];
    float* out = (float*)d_out;

    float* ws     = (float*)d_ws;
    float* down   = ws + OFF_DOWN;
    float* cw     = ws + OFF_CW;
    float* msum   = ws + OFF_MSUM;
    float* tmp    = ws + OFF_TMP;
    float* t_agg  = ws + OFF_TAGG;
    float* anchor = ws + OFF_ANCH;
    float* conf   = ws + OFF_CONF;
    float* rowsum = ws + OFF_RSUM;

    // 1) down-projection GEMM + bias
    k_down<<<dim3(BN/64, MM/64, LL), 256, 0, stream>>>(X, Wd, bd, down);
    // 2) LayerNorm in place
    k_ln<<<(LL*BN)/4, 256, 0, stream>>>(down, gd, betd);
    // 3) masked means
    k_agg<<<dim3(BB, LL), 384, 0, stream>>>(down, len, t_agg, anchor);
    // 4) conf
    k_conf<<<BB, 64, 0, stream>>>(anchor, t_agg, Wg, bg, conf);
    // 5) msum identity term
    k_msum_init<<<(BB*NN*MM)/256, 256, 0, stream>>>(down, conf, msum);
    // 6) per-l: S GEMM -> rowsum -> merged accumulation
    for (int l = 0; l < 12; ++l) {
        k_s     <<<dim3(NN/64, NN/64, BB), 256, 0, stream>>>(down, len, cw, l);
        k_rowsum<<<(BB*NN)/4, 256, 0, stream>>>(cw, rowsum);
        k_merge <<<dim3(NN/64, MM/64, BB), 256, 0, stream>>>(cw, down, rowsum, conf, msum, l);
    }
    // 7) proj GEMM
    k_proj<<<dim3(BN/64, MM/64), 256, 0, stream>>>(msum, Wp, bp, tmp);
    // 8) residual + LN + relu
    k_ln2<<<BN/4, 256, 0, stream>>>(tmp, down, gp, betp);
    // 9) up GEMM -> output
    k_up<<<dim3(BN/64, EE/64), 256, 0, stream>>>(tmp, Wu, bu, out);
    // 10) lengths tail
    k_len<<<1, 64, 0, stream>>>(len, out);
}

// Round 2
// 1334.992 us; speedup vs baseline: 3.3663x; 3.3663x over previous
//
#include <hip/hip_runtime.h>

#define LL 13
#define BB 32
#define NN 512
#define HH 768
#define MM 384
#define EE 768
#define BN (BB*NN)   // 16384

typedef __attribute__((ext_vector_type(8))) short s16x8;
typedef __attribute__((ext_vector_type(4))) float f32x4;
typedef unsigned int u32;
#define AS1 __attribute__((address_space(1)))
#define AS3 __attribute__((address_space(3)))

__device__ __forceinline__ short f2bf(float f) {
    union { float f; u32 u; } c; c.f = f;
    u32 u = c.u;
    return (short)((u + 0x7fffu + ((u >> 16) & 1u)) >> 16);   // RNE
}
__device__ __forceinline__ float bf2f(short h) {
    union { u32 u; float f; } c; c.u = ((u32)(unsigned short)h) << 16;
    return c.f;
}
__device__ __forceinline__ void gload16(const void* g, void* l) {
    __builtin_amdgcn_global_load_lds((const AS1 u32*)g, (AS3 u32*)l, 16, 0, 0);
}

// ============ bf16 MFMA GEMM core: 128x128 tile, BK=32, 4 waves, 16x16x32 ============
// Computes C(128x128) = A(128xK) * B^T(128xK)  -- both operands reduction-contiguous.
// LDS fragment-slot layout: slot(group g, lane l) at base + g*1024 + l*16 holds
// 8 bf16 = source row (g*16 + (l&15)), k-chunk (l>>4) of the current 32-wide K step.
// AFP32: A operand is fp32, reg-staged with on-the-fly cvt; B always bf16 via global_load_lds.
template<bool AFP32>
__device__ __forceinline__ void gemm_core(const char* At, int lda,
                                          const char* Bt, int ldb,
                                          int K, char* lds, f32x4 acc[4][4])
{
    const int tid  = threadIdx.x;
    const int lane = tid & 63;
    const int w    = tid >> 6;
    char* sA = lds;
    char* sB = lds + 8192;
    const int mt0 = (w >> 1) * 4;
    const int nt0 = (w & 1) * 4;

    // staging rows for this wave's two groups (used for B always, for A in bf16 path)
    const int rg0 = (w*2)*16 + (lane & 15);
    const int rg1 = rg0 + 16;
    const int kcb = (lane >> 4) * 16;     // byte offset of this lane's 16B k-chunk
    const char* gb0 = Bt + (size_t)rg0 * ldb * 2 + kcb;
    const char* gb1 = Bt + (size_t)rg1 * ldb * 2 + kcb;
    char* lb0 = sB + (w*2)*1024;
    char* lb1 = lb0 + 1024;

    auto mfma_step = [&]() {
        s16x8 af[4], bf[4];
        #pragma unroll
        for (int i = 0; i < 4; ++i) af[i] = *(const s16x8*)(sA + ((mt0+i)<<10) + lane*16);
        #pragma unroll
        for (int j = 0; j < 4; ++j) bf[j] = *(const s16x8*)(sB + ((nt0+j)<<10) + lane*16);
        #pragma unroll
        for (int i = 0; i < 4; ++i)
            #pragma unroll
            for (int j = 0; j < 4; ++j)
                acc[i][j] = __builtin_amdgcn_mfma_f32_16x16x32_bf16(af[i], bf[j], acc[i][j], 0, 0, 0);
    };

    if (!AFP32) {
        const char* ga0 = At + (size_t)rg0 * lda * 2 + kcb;
        const char* ga1 = At + (size_t)rg1 * lda * 2 + kcb;
        char* la0 = sA + (w*2)*1024;
        char* la1 = la0 + 1024;
        for (int k0 = 0; k0 < K; k0 += 32) {
            __syncthreads();
            gload16(ga0, la0); gload16(ga1, la1);
            gload16(gb0, lb0); gload16(gb1, lb1);
            ga0 += 64; ga1 += 64; gb0 += 64; gb1 += 64;
            __syncthreads();
            mfma_step();
        }
    } else {
        // A: thread stages row r = tid>>1, 16 fp32 at k-half (tid&1)
        const int r  = tid >> 1;
        const int kh = tid & 1;
        const char* ga = At + ((size_t)r * lda + kh*16) * 4;
        char* la = sA + ((r>>4)*64 + (r&15) + (kh*2)*16) * 16;
        for (int k0 = 0; k0 < K; k0 += 32) {
            f32x4 f0 = *(const f32x4*)(ga);
            f32x4 f1 = *(const f32x4*)(ga + 16);
            f32x4 f2 = *(const f32x4*)(ga + 32);
            f32x4 f3 = *(const f32x4*)(ga + 48);
            ga += 128;
            s16x8 v0, v1;
            v0[0]=f2bf(f0[0]); v0[1]=f2bf(f0[1]); v0[2]=f2bf(f0[2]); v0[3]=f2bf(f0[3]);
            v0[4]=f2bf(f1[0]); v0[5]=f2bf(f1[1]); v0[6]=f2bf(f1[2]); v0[7]=f2bf(f1[3]);
            v1[0]=f2bf(f2[0]); v1[1]=f2bf(f2[1]); v1[2]=f2bf(f2[2]); v1[3]=f2bf(f2[3]);
            v1[4]=f2bf(f3[0]); v1[5]=f2bf(f3[1]); v1[6]=f2bf(f3[2]); v1[7]=f2bf(f3[3]);
            __syncthreads();
            gload16(gb0, lb0); gload16(gb1, lb1);
            gb0 += 64; gb1 += 64;
            *(s16x8*)la         = v0;
            *(s16x8*)(la + 256) = v1;
            __syncthreads();
            mfma_step();
        }
    }
}

__device__ __forceinline__ void zero_acc(f32x4 acc[4][4]) {
    #pragma unroll
    for (int i = 0; i < 4; ++i)
        #pragma unroll
        for (int j = 0; j < 4; ++j) {
            acc[i][j][0] = 0.f; acc[i][j][1] = 0.f;
            acc[i][j][2] = 0.f; acc[i][j][3] = 0.f;
        }
}

// ---------------- K0: weight transpose fp32[R][C] -> bf16[C][R] ----------------
__global__ __launch_bounds__(256) void k_wt(const float* __restrict__ in, short* __restrict__ out,
                                            int R, int C, size_t zin, size_t zout)
{
    __shared__ short L[64][80];
    const float* I = in + (size_t)blockIdx.z * zin;
    short* O = out + (size_t)blockIdx.z * zout;
    const int r0 = blockIdx.y * 64, c0 = blockIdx.x * 64;
    const int t = threadIdx.x;
    {
        int r = t >> 2, cq = (t & 3) * 16;
        const float* p = I + (size_t)(r0 + r) * C + c0 + cq;
        s16x8 a, b;
        f32x4 u0 = *(const f32x4*)(p);
        f32x4 u1 = *(const f32x4*)(p + 4);
        f32x4 u2 = *(const f32x4*)(p + 8);
        f32x4 u3 = *(const f32x4*)(p + 12);
        a[0]=f2bf(u0[0]); a[1]=f2bf(u0[1]); a[2]=f2bf(u0[2]); a[3]=f2bf(u0[3]);
        a[4]=f2bf(u1[0]); a[5]=f2bf(u1[1]); a[6]=f2bf(u1[2]); a[7]=f2bf(u1[3]);
        b[0]=f2bf(u2[0]); b[1]=f2bf(u2[1]); b[2]=f2bf(u2[2]); b[3]=f2bf(u2[3]);
        b[4]=f2bf(u3[0]); b[5]=f2bf(u3[1]); b[6]=f2bf(u3[2]); b[7]=f2bf(u3[3]);
        *(s16x8*)&L[r][cq]     = a;
        *(s16x8*)&L[r][cq + 8] = b;
    }
    __syncthreads();
    #pragma unroll
    for (int it = 0; it < 2; ++it) {
        int id = it * 256 + t;
        int cc = id >> 3, rq = id & 7;
        s16x8 v;
        #pragma unroll
        for (int e = 0; e < 8; ++e) v[e] = L[rq*8 + e][cc];
        *(s16x8*)(O + (size_t)(c0 + cc) * R + r0 + rq*8) = v;
    }
}

// ---------------- K1: down GEMM (fp32 A, +bias, bf16 out pre-LN) ----------------
__global__ __launch_bounds__(256) void k_down(const float* __restrict__ X,
                                              const short* __restrict__ WdT,
                                              const float* __restrict__ bd,
                                              short* __restrict__ down)
{
    __shared__ char lds[36864];
    const int l = blockIdx.z;
    const int row0 = blockIdx.x * 128;
    const int col0 = blockIdx.y * 128;
    const char* At = (const char*)(X   + (size_t)l*BN*HH + (size_t)row0*HH);
    const char* Bt = (const char*)(WdT + (size_t)l*MM*HH + (size_t)col0*HH);
    f32x4 acc[4][4]; zero_acc(acc);
    gemm_core<true>(At, HH, Bt, HH, HH, lds, acc);

    const int tid = threadIdx.x, lane = tid & 63, w = tid >> 6;
    const int wr = w >> 1, wc = w & 1;
    float bj[4];
    #pragma unroll
    for (int j = 0; j < 4; ++j) bj[j] = bd[l*MM + col0 + wc*64 + j*16 + (lane & 15)];
    __syncthreads();
    short* ep = (short*)(lds + w * 9216);
    #pragma unroll
    for (int i = 0; i < 4; ++i) {
        int rr = i*16 + (lane >> 4) * 4;
        #pragma unroll
        for (int j = 0; j < 4; ++j) {
            int cc = j*16 + (lane & 15);
            #pragma unroll
            for (int r = 0; r < 4; ++r)
                ep[(rr + r)*72 + cc] = f2bf(acc[i][j][r] + bj[j]);
        }
    }
    __syncthreads();
    short* C = down + (size_t)l*BN*MM;
    #pragma unroll
    for (int it = 0; it < 8; ++it) {
        int c = it*64 + lane;
        int row = c >> 3, kq = c & 7;
        s16x8 v = *(const s16x8*)(ep + row*72 + kq*8);
        int grow = row0 + wr*64 + row;
        int gcol = col0 + wc*64 + kq*8;
        *(s16x8*)(C + (size_t)grow*MM + gcol) = v;
    }
}

// ---------------- K2: LayerNorm in place (bf16) + transposed copy for l<12 ----------------
__global__ __launch_bounds__(256) void k_ln(short* __restrict__ down,
                                            const float* __restrict__ g,
                                            const float* __restrict__ beta,
                                            short* __restrict__ downT)
{
    __shared__ short Lt[64][392];
    const int blk = blockIdx.x;
    const int l = blk / (BB*8);
    const int rem = blk % (BB*8);
    const int b = rem >> 3;
    const int n0 = (rem & 7) * 64;
    const int tid = threadIdx.x, lane = tid & 63, w = tid >> 6;

    for (int it = 0; it < 16; ++it) {
        int ri = it*4 + w;
        int n = n0 + ri;
        short* p = down + (((size_t)l*BB + b)*NN + n) * MM;
        float v[6]; float s = 0.f, s2 = 0.f;
        #pragma unroll
        for (int t = 0; t < 6; ++t) { v[t] = bf2f(p[lane + t*64]); s += v[t]; s2 += v[t]*v[t]; }
        #pragma unroll
        for (int off = 32; off; off >>= 1) { s += __shfl_xor(s, off); s2 += __shfl_xor(s2, off); }
        float mu  = s * (1.f/MM);
        float inv = rsqrtf(s2 * (1.f/MM) - mu*mu + 1e-5f);
        #pragma unroll
        for (int t = 0; t < 6; ++t) {
            int m = lane + t*64;
            short o = f2bf((v[t]-mu)*inv * g[l*MM + m] + beta[l*MM + m]);
            p[m] = o;
            Lt[ri][m] = o;
        }
    }
    if (l == 12) return;
    __syncthreads();
    short* O = downT + ((size_t)(l*BB + b)) * MM * NN;   // [384][512]
    #pragma unroll
    for (int it = 0; it < 12; ++it) {
        int id = it*256 + tid;
        int m = id >> 3, nq = id & 7;
        s16x8 vv;
        #pragma unroll
        for (int e = 0; e < 8; ++e) vv[e] = Lt[nq*8 + e][m];
        *(s16x8*)(O + (size_t)m*NN + n0 + nq*8) = vv;
    }
}

// ---------------- K3: masked means ----------------
__global__ __launch_bounds__(384) void k_agg(const short* __restrict__ down,
                                             const int* __restrict__ lengths,
                                             float* __restrict__ t_agg,
                                             float* __restrict__ anchor)
{
    const int b = blockIdx.x;
    const int l = blockIdx.y;
    const int m = threadIdx.x;
    const int len = lengths[b];
    const short* p = down + ((size_t)l*BB + b)*NN*MM;
    float s = 0.f;
    for (int n = 0; n < len; ++n) s += bf2f(p[(size_t)n*MM + m]);
    s /= (float)len;
    if (l == 12) anchor[b*MM + m] = s;
    else         t_agg[((size_t)l*BB + b)*MM + m] = s;
}

// ---------------- K4: conf ----------------
__global__ __launch_bounds__(64) void k_conf(const float* __restrict__ anchor,
                                             const float* __restrict__ t_agg,
                                             const float* __restrict__ Wg,
                                             const float* __restrict__ bg,
                                             float* __restrict__ conf)
{
    const int b = blockIdx.x;
    const int lane = threadIdx.x;
    float lg[12];
    #pragma unroll
    for (int l = 0; l < 12; ++l) {
        float s = 0.f;
        #pragma unroll
        for (int t = 0; t < 6; ++t) {
            int m = lane + t*64;
            s += anchor[b*MM + m] * t_agg[((size_t)l*BB + b)*MM + m] * Wg[m];
        }
        #pragma unroll
        for (int off = 32; off; off >>= 1) s += __shfl_xor(s, off);
        lg[l] = s + bg[0];
    }
    float mx = lg[0];
    #pragma unroll
    for (int l = 1; l < 12; ++l) mx = fmaxf(mx, lg[l]);
    float den = 0.f, e[12];
    #pragma unroll
    for (int l = 0; l < 12; ++l) { e[l] = expf(lg[l]-mx); den += e[l]; }
    if (lane == 0) {
        #pragma unroll
        for (int l = 0; l < 12; ++l) conf[b*12 + l] = e[l]/den;
    }
}

// ---------------- K5: msum identity term ----------------
__global__ __launch_bounds__(256) void k_msum_init(const short* __restrict__ down,
                                                   const float* __restrict__ conf,
                                                   float* __restrict__ msum)
{
    size_t i8 = ((size_t)blockIdx.x*256 + threadIdx.x) * 8;
    int b = (int)(i8 / ((size_t)NN*MM));
    float o[8] = {0,0,0,0,0,0,0,0};
    #pragma unroll
    for (int l = 0; l < 12; ++l) {
        s16x8 v = *(const s16x8*)(down + (size_t)l*BN*MM + i8);
        float c = conf[b*12 + l];
        #pragma unroll
        for (int e = 0; e < 8; ++e) o[e] += c * bf2f(v[e]);
    }
    f32x4 a = {o[0],o[1],o[2],o[3]}, bb = {o[4],o[5],o[6],o[7]};
    *(f32x4*)(msum + i8)     = a;
    *(f32x4*)(msum + i8 + 4) = bb;
}

// ---------------- K6: S = anchor_feat @ targets^T (relu, col-mask, bf16 out) ----------------
__global__ __launch_bounds__(256) void k_s(const short* __restrict__ down,
                                           const int* __restrict__ lengths,
                                           short* __restrict__ cw, int l)
{
    __shared__ char lds[36864];
    const int b = blockIdx.z;
    const int row0 = blockIdx.x * 128;
    const int col0 = blockIdx.y * 128;
    const char* At = (const char*)(down + ((size_t)12*BB + b)*NN*MM + (size_t)row0*MM);
    const char* Bt = (const char*)(down + ((size_t)l*BB  + b)*NN*MM + (size_t)col0*MM);
    f32x4 acc[4][4]; zero_acc(acc);
    gemm_core<false>(At, MM, Bt, MM, MM, lds, acc);

    const int tid = threadIdx.x, lane = tid & 63, w = tid >> 6;
    const int wr = w >> 1, wc = w & 1;
    const int len = lengths[b];
    __syncthreads();
    short* ep = (short*)(lds + w * 9216);
    #pragma unroll
    for (int i = 0; i < 4; ++i) {
        int rr = i*16 + (lane >> 4) * 4;
        #pragma unroll
        for (int j = 0; j < 4; ++j) {
            int cc = j*16 + (lane & 15);
            bool keep = (col0 + wc*64 + cc) < len;
            #pragma unroll
            for (int r = 0; r < 4; ++r) {
                float v = keep ? fmaxf(acc[i][j][r], 0.f) : 0.f;
                ep[(rr + r)*72 + cc] = f2bf(v);
            }
        }
    }
    __syncthreads();
    short* C = cw + (size_t)b*NN*NN;
    #pragma unroll
    for (int it = 0; it < 8; ++it) {
        int c = it*64 + lane;
        int row = c >> 3, kq = c & 7;
        s16x8 v = *(const s16x8*)(ep + row*72 + kq*8);
        int grow = row0 + wr*64 + row;
        int gcol = col0 + wc*64 + kq*8;
        *(s16x8*)(C + (size_t)grow*NN + gcol) = v;
    }
}

// ---------------- K6b: row sums of cw ----------------
__global__ __launch_bounds__(256) void k_rowsum(const short* __restrict__ cw,
                                                float* __restrict__ rowsum)
{
    const int row  = blockIdx.x*4 + (threadIdx.x >> 6);
    const int lane = threadIdx.x & 63;
    s16x8 v = *(const s16x8*)(cw + (size_t)row*NN + lane*8);
    float s = 0.f;
    #pragma unroll
    for (int e = 0; e < 8; ++e) s += bf2f(v[e]);
    #pragma unroll
    for (int off = 32; off; off >>= 1) s += __shfl_xor(s, off);
    if (lane == 0) rowsum[row] = s;
}

// ---------------- K7: msum += conf/(rowsum+eps) * (cw @ targets) ----------------
__global__ __launch_bounds__(256) void k_merge(const short* __restrict__ cw,
                                               const short* __restrict__ downT,
                                               const float* __restrict__ rowsum,
                                               const float* __restrict__ conf,
                                               float* __restrict__ msum, int l)
{
    __shared__ char lds[16384];
    const int b = blockIdx.z;
    const int row0 = blockIdx.x * 128;
    const int col0 = blockIdx.y * 128;
    const char* At = (const char*)(cw + (size_t)b*NN*NN + (size_t)row0*NN);
    const char* Bt = (const char*)(downT + ((size_t)(l*BB + b))*MM*NN + (size_t)col0*NN);
    f32x4 acc[4][4]; zero_acc(acc);
    gemm_core<false>(At, NN, Bt, NN, NN, lds, acc);

    const int tid = threadIdx.x, lane = tid & 63, w = tid >> 6;
    const int wr = w >> 1, wc = w & 1;
    const float cf = conf[b*12 + l];
    #pragma unroll
    for (int i = 0; i < 4; ++i) {
        #pragma unroll
        for (int r = 0; r < 4; ++r) {
            int n = row0 + wr*64 + i*16 + (lane >> 4)*4 + r;
            float sc = cf / (rowsum[b*NN + n] + 1e-8f);
            #pragma unroll
            for (int j = 0; j < 4; ++j) {
                int m = col0 + wc*64 + j*16 + (lane & 15);
                float* p = &msum[((size_t)b*NN + n)*MM + m];
                *p += sc * acc[i][j][r];
            }
        }
    }
}

// ---------------- K8: proj GEMM (fp32 A, fp32 C + bias) ----------------
__global__ __launch_bounds__(256) void k_proj(const float* __restrict__ msum,
                                              const short* __restrict__ WpT,
                                              const float* __restrict__ bp,
                                              float* __restrict__ tmp)
{
    __shared__ char lds[16384];
    const int row0 = blockIdx.x * 128;
    const int col0 = blockIdx.y * 128;
    const char* At = (const char*)(msum + (size_t)row0*MM);
    const char* Bt = (const char*)(WpT + (size_t)col0*MM);
    f32x4 acc[4][4]; zero_acc(acc);
    gemm_core<true>(At, MM, Bt, MM, MM, lds, acc);

    const int tid = threadIdx.x, lane = tid & 63, w = tid >> 6;
    const int wr = w >> 1, wc = w & 1;
    float bj[4];
    #pragma unroll
    for (int j = 0; j < 4; ++j) bj[j] = bp[col0 + wc*64 + j*16 + (lane & 15)];
    #pragma unroll
    for (int i = 0; i < 4; ++i)
        #pragma unroll
        for (int r = 0; r < 4; ++r) {
            int grow = row0 + wr*64 + i*16 + (lane >> 4)*4 + r;
            #pragma unroll
            for (int j = 0; j < 4; ++j) {
                int gcol = col0 + wc*64 + j*16 + (lane & 15);
                tmp[(size_t)grow*MM + gcol] = acc[i][j][r] + bj[j];
            }
        }
}

// ---------------- K9: R = relu(anchor_feat + LN(tmp)), bf16 out ----------------
__global__ __launch_bounds__(256) void k_ln2(const float* __restrict__ tmp,
                                             const short* __restrict__ down,
                                             const float* __restrict__ g,
                                             const float* __restrict__ beta,
                                             short* __restrict__ R)
{
    const int row  = blockIdx.x*4 + (threadIdx.x >> 6);
    const int lane = threadIdx.x & 63;
    const float* p = tmp + (size_t)row*MM;
    const short* af = down + (size_t)12*BN*MM + (size_t)row*MM;
    float v[6]; float s = 0.f, s2 = 0.f;
    #pragma unroll
    for (int t = 0; t < 6; ++t) { v[t] = p[lane + t*64]; s += v[t]; s2 += v[t]*v[t]; }
    #pragma unroll
    for (int off = 32; off; off >>= 1) { s += __shfl_xor(s, off); s2 += __shfl_xor(s2, off); }
    float mu  = s * (1.f/MM);
    float inv = rsqrtf(s2 * (1.f/MM) - mu*mu + 1e-5f);
    #pragma unroll
    for (int t = 0; t < 6; ++t) {
        int m = lane + t*64;
        float o = bf2f(af[m]) + (v[t]-mu)*inv * g[m] + beta[m];
        R[(size_t)row*MM + m] = f2bf(fmaxf(o, 0.f));
    }
}

// ---------------- K10: up GEMM (bf16 A, fp32 C + bias) -> d_out ----------------
__global__ __launch_bounds__(256) void k_up(const short* __restrict__ R,
                                            const short* __restrict__ WuT,
                                            const float* __restrict__ bu,
                                            float* __restrict__ Y)
{
    __shared__ char lds[16384];
    const int row0 = blockIdx.x * 128;
    const int col0 = blockIdx.y * 128;
    const char* At = (const char*)(R + (size_t)row0*MM);
    const char* Bt = (const char*)(WuT + (size_t)col0*MM);
    f32x4 acc[4][4]; zero_acc(acc);
    gemm_core<false>(At, MM, Bt, MM, MM, lds, acc);

    const int tid = threadIdx.x, lane = tid & 63, w = tid >> 6;
    const int wr = w >> 1, wc = w & 1;
    float bj[4];
    #pragma unroll
    for (int j = 0; j < 4; ++j) bj[j] = bu[col0 + wc*64 + j*16 + (lane & 15)];
    #pragma unroll
    for (int i = 0; i < 4; ++i)
        #pragma unroll
        for (int r = 0; r < 4; ++r) {
            int grow = row0 + wr*64 + i*16 + (lane >> 4)*4 + r;
            #pragma unroll
            for (int j = 0; j < 4; ++j) {
                int gcol = col0 + wc*64 + j*16 + (lane & 15);
                Y[(size_t)grow*EE + gcol] = acc[i][j][r] + bj[j];
            }
        }
}

// ---------------- K11: lengths tail ----------------
__global__ void k_len(const int* __restrict__ lengths, float* __restrict__ out)
{
    if (threadIdx.x < BB)
        out[(size_t)BB*NN*EE + threadIdx.x] = (float)lengths[threadIdx.x];
}

extern "C" void kernel_launch(void* const* d_in, const int* in_sizes, int n_in,
                              void* d_out, int out_size, void* d_ws, size_t ws_size,
                              hipStream_t stream)
{
    const float* X    = (const float*)d_in[0];
    const int*   len  = (const int*)  d_in[1];
    const float* Wd   = (const float*)d_in[2];
    const float* bd   = (const float*)d_in[3];
    const float* gd   = (const float*)d_in[4];
    const float* betd = (const float*)d_in[5];
    const float* Wp   = (const float*)d_in[6];
    const float* bp   = (const float*)d_in[7];
    const float* gp   = (const float*)d_in[8];
    const float* betp = (const float*)d_in[9];
    const float* Wu   = (const float*)d_in[10];
    const float* bu   = (const float*)d_in[11];
    const float* Wg   = (const float*)d_in[12];
    const float* bg   = (const float*)d_in[13];
    float* out = (float*)d_out;

    // workspace layout
    float* ws     = (float*)d_ws;
    float* msum   = ws;                          // 6291456 f
    float* tmp    = msum + 6291456;              // 6291456 f
    float* t_agg  = tmp + 6291456;               // 147456 f
    float* anchor = t_agg + 147456;              // 12288 f
    float* conf   = anchor + 12288;              // 384 f
    float* rowsum = conf + 384;                  // 16384 f
    short* down   = (short*)(rowsum + 16384);    // 81788928 sh
    short* downT  = down  + (size_t)81788928;    // 75497472 sh
    short* cw     = downT + (size_t)75497472;    // 8388608 sh
    short* R      = cw    + (size_t)8388608;     // 6291456 sh
    short* WdT    = R     + (size_t)6291456;     // 3833856 sh
    short* WpT    = WdT   + (size_t)3833856;     // 147456 sh
    short* WuT    = WpT   + (size_t)147456;      // 294912 sh

    // 0) weight transposes -> bf16
    k_wt<<<dim3(6, 12, 13), 256, 0, stream>>>(Wd, WdT, HH, MM, (size_t)HH*MM, (size_t)HH*MM);
    k_wt<<<dim3(6, 6, 1),   256, 0, stream>>>(Wp, WpT, MM, MM, 0, 0);
    k_wt<<<dim3(12, 6, 1),  256, 0, stream>>>(Wu, WuT, MM, EE, 0, 0);
    // 1) down GEMM (pre-LN bf16)
    k_down<<<dim3(BN/128, MM/128, LL), 256, 0, stream>>>(X, WdT, bd, down);
    // 2) LN in place + transposed copy
    k_ln<<<LL*BB*8, 256, 0, stream>>>(down, gd, betd, downT);
    // 3) masked means
    k_agg<<<dim3(BB, LL), 384, 0, stream>>>(down, len, t_agg, anchor);
    // 4) conf
    k_conf<<<BB, 64, 0, stream>>>(anchor, t_agg, Wg, bg, conf);
    // 5) msum identity term
    k_msum_init<<<(BB*NN*MM)/(256*8), 256, 0, stream>>>(down, conf, msum);
    // 6) per-l: S -> rowsum -> merge
    for (int l = 0; l < 12; ++l) {
        k_s     <<<dim3(NN/128, NN/128, BB), 256, 0, stream>>>(down, len, cw, l);
        k_rowsum<<<(BB*NN)/4, 256, 0, stream>>>(cw, rowsum);
        k_merge <<<dim3(NN/128, MM/128, BB), 256, 0, stream>>>(cw, downT, rowsum, conf, msum, l);
    }
    // 7) proj
    k_proj<<<dim3(BN/128, MM/128), 256, 0, stream>>>(msum, WpT, bp, tmp);
    // 8) residual + LN + relu -> bf16
    k_ln2<<<BN/4, 256, 0, stream>>>(tmp, down, gp, betp, R);
    // 9) up -> out
    k_up<<<dim3(BN/128, EE/128), 256, 0, stream>>>(R, WuT, bu, out);
    // 10) lengths tail
    k_len<<<1, 64, 0, stream>>>(len, out);
}

// Round 3
// 1179.623 us; speedup vs baseline: 3.8097x; 1.1317x over previous
//
#include <hip/hip_runtime.h>

#define LL 13
#define BB 32
#define NN 512
#define HH 768
#define MM 384
#define EE 768
#define BN (BB*NN)   // 16384
#define K12 (12*NN)  // 6144

typedef __attribute__((ext_vector_type(8))) short s16x8;
typedef __attribute__((ext_vector_type(4))) float f32x4;
typedef unsigned int u32;
#define AS1 __attribute__((address_space(1)))
#define AS3 __attribute__((address_space(3)))

__device__ __forceinline__ short f2bf(float f) {
    union { float f; u32 u; } c; c.f = f;
    u32 u = c.u;
    return (short)((u + 0x7fffu + ((u >> 16) & 1u)) >> 16);   // RNE
}
__device__ __forceinline__ float bf2f(short h) {
    union { u32 u; float f; } c; c.u = ((u32)(unsigned short)h) << 16;
    return c.f;
}
__device__ __forceinline__ void gload16(const void* g, void* l) {
    __builtin_amdgcn_global_load_lds((const AS1 u32*)g, (AS3 u32*)l, 16, 0, 0);
}

// ============ bf16 MFMA GEMM core: 128x128 tile, BK=32, 4 waves, 16x16x32 ============
// C(128x128) = A(128xK) * B^T(128xK), both operands reduction-contiguous.
// LDS slots: base + g*1024 + lane*16 holds row (g*16 + (lane&15)), k-chunk (lane>>4).
template<bool AFP32>
__device__ __forceinline__ void gemm_core(const char* At, int lda,
                                          const char* Bt, int ldb,
                                          int K, char* lds, f32x4 acc[4][4])
{
    const int tid  = threadIdx.x;
    const int lane = tid & 63;
    const int w    = tid >> 6;
    char* sA = lds;
    char* sB = lds + 8192;
    const int mt0 = (w >> 1) * 4;
    const int nt0 = (w & 1) * 4;

    const int rg0 = (w*2)*16 + (lane & 15);
    const int rg1 = rg0 + 16;
    const int kcb = (lane >> 4) * 16;
    const char* gb0 = Bt + (size_t)rg0 * ldb * 2 + kcb;
    const char* gb1 = Bt + (size_t)rg1 * ldb * 2 + kcb;
    char* lb0 = sB + (w*2)*1024;
    char* lb1 = lb0 + 1024;

    auto mfma_step = [&]() {
        s16x8 af[4], bf[4];
        #pragma unroll
        for (int i = 0; i < 4; ++i) af[i] = *(const s16x8*)(sA + ((mt0+i)<<10) + lane*16);
        #pragma unroll
        for (int j = 0; j < 4; ++j) bf[j] = *(const s16x8*)(sB + ((nt0+j)<<10) + lane*16);
        #pragma unroll
        for (int i = 0; i < 4; ++i)
            #pragma unroll
            for (int j = 0; j < 4; ++j)
                acc[i][j] = __builtin_amdgcn_mfma_f32_16x16x32_bf16(af[i], bf[j], acc[i][j], 0, 0, 0);
    };

    if (!AFP32) {
        const char* ga0 = At + (size_t)rg0 * lda * 2 + kcb;
        const char* ga1 = At + (size_t)rg1 * lda * 2 + kcb;
        char* la0 = sA + (w*2)*1024;
        char* la1 = la0 + 1024;
        for (int k0 = 0; k0 < K; k0 += 32) {
            __syncthreads();
            gload16(ga0, la0); gload16(ga1, la1);
            gload16(gb0, lb0); gload16(gb1, lb1);
            ga0 += 64; ga1 += 64; gb0 += 64; gb1 += 64;
            __syncthreads();
            mfma_step();
        }
    } else {
        const int r  = tid >> 1;
        const int kh = tid & 1;
        const char* ga = At + ((size_t)r * lda + kh*16) * 4;
        char* la = sA + ((r>>4)*64 + (r&15) + (kh*2)*16) * 16;
        for (int k0 = 0; k0 < K; k0 += 32) {
            f32x4 f0 = *(const f32x4*)(ga);
            f32x4 f1 = *(const f32x4*)(ga + 16);
            f32x4 f2 = *(const f32x4*)(ga + 32);
            f32x4 f3 = *(const f32x4*)(ga + 48);
            ga += 128;
            s16x8 v0, v1;
            v0[0]=f2bf(f0[0]); v0[1]=f2bf(f0[1]); v0[2]=f2bf(f0[2]); v0[3]=f2bf(f0[3]);
            v0[4]=f2bf(f1[0]); v0[5]=f2bf(f1[1]); v0[6]=f2bf(f1[2]); v0[7]=f2bf(f1[3]);
            v1[0]=f2bf(f2[0]); v1[1]=f2bf(f2[1]); v1[2]=f2bf(f2[2]); v1[3]=f2bf(f2[3]);
            v1[4]=f2bf(f3[0]); v1[5]=f2bf(f3[1]); v1[6]=f2bf(f3[2]); v1[7]=f2bf(f3[3]);
            __syncthreads();
            gload16(gb0, lb0); gload16(gb1, lb1);
            gb0 += 64; gb1 += 64;
            *(s16x8*)la         = v0;
            *(s16x8*)(la + 256) = v1;
            __syncthreads();
            mfma_step();
        }
    }
}

__device__ __forceinline__ void zero_acc(f32x4 acc[4][4]) {
    #pragma unroll
    for (int i = 0; i < 4; ++i)
        #pragma unroll
        for (int j = 0; j < 4; ++j) {
            acc[i][j][0] = 0.f; acc[i][j][1] = 0.f;
            acc[i][j][2] = 0.f; acc[i][j][3] = 0.f;
        }
}

// ---------------- K0: weight transpose fp32[R][C] -> bf16[C][R] ----------------
__global__ __launch_bounds__(256) void k_wt(const float* __restrict__ in, short* __restrict__ out,
                                            int R, int C, size_t zin, size_t zout)
{
    __shared__ short L[64][80];
    const float* I = in + (size_t)blockIdx.z * zin;
    short* O = out + (size_t)blockIdx.z * zout;
    const int r0 = blockIdx.y * 64, c0 = blockIdx.x * 64;
    const int t = threadIdx.x;
    {
        int r = t >> 2, cq = (t & 3) * 16;
        const float* p = I + (size_t)(r0 + r) * C + c0 + cq;
        s16x8 a, b;
        f32x4 u0 = *(const f32x4*)(p);
        f32x4 u1 = *(const f32x4*)(p + 4);
        f32x4 u2 = *(const f32x4*)(p + 8);
        f32x4 u3 = *(const f32x4*)(p + 12);
        a[0]=f2bf(u0[0]); a[1]=f2bf(u0[1]); a[2]=f2bf(u0[2]); a[3]=f2bf(u0[3]);
        a[4]=f2bf(u1[0]); a[5]=f2bf(u1[1]); a[6]=f2bf(u1[2]); a[7]=f2bf(u1[3]);
        b[0]=f2bf(u2[0]); b[1]=f2bf(u2[1]); b[2]=f2bf(u2[2]); b[3]=f2bf(u2[3]);
        b[4]=f2bf(u3[0]); b[5]=f2bf(u3[1]); b[6]=f2bf(u3[2]); b[7]=f2bf(u3[3]);
        *(s16x8*)&L[r][cq]     = a;
        *(s16x8*)&L[r][cq + 8] = b;
    }
    __syncthreads();
    #pragma unroll
    for (int it = 0; it < 2; ++it) {
        int id = it * 256 + t;
        int cc = id >> 3, rq = id & 7;
        s16x8 v;
        #pragma unroll
        for (int e = 0; e < 8; ++e) v[e] = L[rq*8 + e][cc];
        *(s16x8*)(O + (size_t)(c0 + cc) * R + r0 + rq*8) = v;
    }
}

// ---------------- K1: down GEMM (fp32 A, +bias, bf16 out pre-LN) ----------------
__global__ __launch_bounds__(256) void k_down(const float* __restrict__ X,
                                              const short* __restrict__ WdT,
                                              const float* __restrict__ bd,
                                              short* __restrict__ down)
{
    __shared__ char lds[36864];
    const int l = blockIdx.z;
    const int col0 = blockIdx.x * 128;   // x = col tiles (3) -> adjacent blocks share A rows
    const int row0 = blockIdx.y * 128;
    const char* At = (const char*)(X   + (size_t)l*BN*HH + (size_t)row0*HH);
    const char* Bt = (const char*)(WdT + (size_t)l*MM*HH + (size_t)col0*HH);
    f32x4 acc[4][4]; zero_acc(acc);
    gemm_core<true>(At, HH, Bt, HH, HH, lds, acc);

    const int tid = threadIdx.x, lane = tid & 63, w = tid >> 6;
    const int wr = w >> 1, wc = w & 1;
    float bj[4];
    #pragma unroll
    for (int j = 0; j < 4; ++j) bj[j] = bd[l*MM + col0 + wc*64 + j*16 + (lane & 15)];
    __syncthreads();
    short* ep = (short*)(lds + w * 9216);
    #pragma unroll
    for (int i = 0; i < 4; ++i) {
        int rr = i*16 + (lane >> 4) * 4;
        #pragma unroll
        for (int j = 0; j < 4; ++j) {
            int cc = j*16 + (lane & 15);
            #pragma unroll
            for (int r = 0; r < 4; ++r)
                ep[(rr + r)*72 + cc] = f2bf(acc[i][j][r] + bj[j]);
        }
    }
    __syncthreads();
    short* C = down + (size_t)l*BN*MM;
    #pragma unroll
    for (int it = 0; it < 8; ++it) {
        int c = it*64 + lane;
        int row = c >> 3, kq = c & 7;
        s16x8 v = *(const s16x8*)(ep + row*72 + kq*8);
        int grow = row0 + wr*64 + row;
        int gcol = col0 + wc*64 + kq*8;
        *(s16x8*)(C + (size_t)grow*MM + gcol) = v;
    }
}

// ---------------- K2: LN in place (bf16) + transposed copy downTb[b][m][l][n] for l<12 ----------------
__global__ __launch_bounds__(256) void k_ln(short* __restrict__ down,
                                            const float* __restrict__ g,
                                            const float* __restrict__ beta,
                                            short* __restrict__ downTb)
{
    __shared__ short Lt[64][392];
    const int blk = blockIdx.x;
    const int l = blk / (BB*8);
    const int rem = blk % (BB*8);
    const int b = rem >> 3;
    const int n0 = (rem & 7) * 64;
    const int tid = threadIdx.x, lane = tid & 63, w = tid >> 6;

    for (int it = 0; it < 16; ++it) {
        int ri = it*4 + w;
        int n = n0 + ri;
        short* p = down + (((size_t)l*BB + b)*NN + n) * MM;
        float v[6]; float s = 0.f, s2 = 0.f;
        #pragma unroll
        for (int t = 0; t < 6; ++t) { v[t] = bf2f(p[lane + t*64]); s += v[t]; s2 += v[t]*v[t]; }
        #pragma unroll
        for (int off = 32; off; off >>= 1) { s += __shfl_xor(s, off); s2 += __shfl_xor(s2, off); }
        float mu  = s * (1.f/MM);
        float inv = rsqrtf(s2 * (1.f/MM) - mu*mu + 1e-5f);
        #pragma unroll
        for (int t = 0; t < 6; ++t) {
            int m = lane + t*64;
            short o = f2bf((v[t]-mu)*inv * g[l*MM + m] + beta[l*MM + m]);
            p[m] = o;
            Lt[ri][m] = o;
        }
    }
    if (l == 12) return;
    __syncthreads();
    short* O = downTb + ((size_t)b*MM*12 + l) * NN;   // + m*12*NN + n
    #pragma unroll
    for (int it = 0; it < 12; ++it) {
        int id = it*256 + tid;
        int m = id >> 3, nq = id & 7;
        s16x8 vv;
        #pragma unroll
        for (int e = 0; e < 8; ++e) vv[e] = Lt[nq*8 + e][m];
        *(s16x8*)(O + (size_t)m*12*NN + n0 + nq*8) = vv;
    }
}

// ---------------- K3: masked means ----------------
__global__ __launch_bounds__(384) void k_agg(const short* __restrict__ down,
                                             const int* __restrict__ lengths,
                                             float* __restrict__ t_agg,
                                             float* __restrict__ anchor)
{
    const int b = blockIdx.x;
    const int l = blockIdx.y;
    const int m = threadIdx.x;
    const int len = lengths[b];
    const short* p = down + ((size_t)l*BB + b)*NN*MM;
    float s = 0.f;
    for (int n = 0; n < len; ++n) s += bf2f(p[(size_t)n*MM + m]);
    s /= (float)len;
    if (l == 12) anchor[b*MM + m] = s;
    else         t_agg[((size_t)l*BB + b)*MM + m] = s;
}

// ---------------- K4: conf ----------------
__global__ __launch_bounds__(64) void k_conf(const float* __restrict__ anchor,
                                             const float* __restrict__ t_agg,
                                             const float* __restrict__ Wg,
                                             const float* __restrict__ bg,
                                             float* __restrict__ conf)
{
    const int b = blockIdx.x;
    const int lane = threadIdx.x;
    float lg[12];
    #pragma unroll
    for (int l = 0; l < 12; ++l) {
        float s = 0.f;
        #pragma unroll
        for (int t = 0; t < 6; ++t) {
            int m = lane + t*64;
            s += anchor[b*MM + m] * t_agg[((size_t)l*BB + b)*MM + m] * Wg[m];
        }
        #pragma unroll
        for (int off = 32; off; off >>= 1) s += __shfl_xor(s, off);
        lg[l] = s + bg[0];
    }
    float mx = lg[0];
    #pragma unroll
    for (int l = 1; l < 12; ++l) mx = fmaxf(mx, lg[l]);
    float den = 0.f, e[12];
    #pragma unroll
    for (int l = 0; l < 12; ++l) { e[l] = expf(lg[l]-mx); den += e[l]; }
    if (lane == 0) {
        #pragma unroll
        for (int l = 0; l < 12; ++l) conf[b*12 + l] = e[l]/den;
    }
}

// ---------------- K5: S = anchor_feat @ targets^T (relu, col-mask) -> cw[b][n][l*512+k] ----------------
__global__ __launch_bounds__(256) void k_s(const short* __restrict__ down,
                                           const int* __restrict__ lengths,
                                           short* __restrict__ cw)
{
    __shared__ char lds[36864];
    const int b = blockIdx.z / 12;
    const int l = blockIdx.z % 12;
    const int col0 = blockIdx.x * 128;
    const int row0 = blockIdx.y * 128;
    const char* At = (const char*)(down + ((size_t)12*BB + b)*NN*MM + (size_t)row0*MM);
    const char* Bt = (const char*)(down + ((size_t)l*BB  + b)*NN*MM + (size_t)col0*MM);
    f32x4 acc[4][4]; zero_acc(acc);
    gemm_core<false>(At, MM, Bt, MM, MM, lds, acc);

    const int tid = threadIdx.x, lane = tid & 63, w = tid >> 6;
    const int wr = w >> 1, wc = w & 1;
    const int len = lengths[b];
    __syncthreads();
    short* ep = (short*)(lds + w * 9216);
    #pragma unroll
    for (int i = 0; i < 4; ++i) {
        int rr = i*16 + (lane >> 4) * 4;
        #pragma unroll
        for (int j = 0; j < 4; ++j) {
            int cc = j*16 + (lane & 15);
            bool keep = (col0 + wc*64 + cc) < len;
            #pragma unroll
            for (int r = 0; r < 4; ++r) {
                float v = keep ? fmaxf(acc[i][j][r], 0.f) : 0.f;
                ep[(rr + r)*72 + cc] = f2bf(v);
            }
        }
    }
    __syncthreads();
    short* C = cw + ((size_t)b*NN + row0 + wr*64)*K12 + (size_t)l*NN + col0 + wc*64;
    #pragma unroll
    for (int it = 0; it < 8; ++it) {
        int c = it*64 + lane;
        int row = c >> 3, kq = c & 7;
        s16x8 v = *(const s16x8*)(ep + row*72 + kq*8);
        *(s16x8*)(C + (size_t)row*K12 + kq*8) = v;
    }
}

// ---------------- K6: normalize cw rows: cw = conf*(cw/(rowsum+eps)), diag += conf ----------------
__global__ __launch_bounds__(256) void k_norm(short* __restrict__ cw,
                                              const float* __restrict__ conf)
{
    const int rid  = blockIdx.x*4 + (threadIdx.x >> 6);
    const int lane = threadIdx.x & 63;
    const int b   = rid / (NN*12);
    const int rem = rid % (NN*12);
    const int n   = rem / 12;
    const int l   = rem % 12;
    short* p = cw + ((size_t)b*NN + n)*K12 + (size_t)l*NN + lane*8;
    s16x8 v = *(const s16x8*)p;
    float f[8]; float s = 0.f;
    #pragma unroll
    for (int e = 0; e < 8; ++e) { f[e] = bf2f(v[e]); s += f[e]; }
    #pragma unroll
    for (int off = 32; off; off >>= 1) s += __shfl_xor(s, off);
    const float cf = conf[b*12 + l];
    const float sc = cf / (s + 1e-8f);
    #pragma unroll
    for (int e = 0; e < 8; ++e) {
        float o = f[e] * sc;
        if (lane*8 + e == n) o += cf;          // identity (+eye) folded in, pre-scaled by conf
        v[e] = f2bf(o);
    }
    *(s16x8*)p = v;
}

// ---------------- K7: msum[b] = cw_norm[b] @ targetsT_all[b], K=6144, bf16 out ----------------
__global__ __launch_bounds__(256) void k_merge(const short* __restrict__ cw,
                                               const short* __restrict__ downTb,
                                               short* __restrict__ msum)
{
    __shared__ char lds[36864];
    const int b = blockIdx.z;
    const int col0 = blockIdx.x * 128;
    const int row0 = blockIdx.y * 128;
    const char* At = (const char*)(cw     + ((size_t)b*NN + row0)*K12);
    const char* Bt = (const char*)(downTb + ((size_t)b*MM + col0)*K12);
    f32x4 acc[4][4]; zero_acc(acc);
    gemm_core<false>(At, K12, Bt, K12, K12, lds, acc);

    const int tid = threadIdx.x, lane = tid & 63, w = tid >> 6;
    const int wr = w >> 1, wc = w & 1;
    __syncthreads();
    short* ep = (short*)(lds + w * 9216);
    #pragma unroll
    for (int i = 0; i < 4; ++i) {
        int rr = i*16 + (lane >> 4) * 4;
        #pragma unroll
        for (int j = 0; j < 4; ++j) {
            int cc = j*16 + (lane & 15);
            #pragma unroll
            for (int r = 0; r < 4; ++r)
                ep[(rr + r)*72 + cc] = f2bf(acc[i][j][r]);
        }
    }
    __syncthreads();
    short* C = msum + ((size_t)b*NN + row0 + wr*64)*MM + col0 + wc*64;
    #pragma unroll
    for (int it = 0; it < 8; ++it) {
        int c = it*64 + lane;
        int row = c >> 3, kq = c & 7;
        s16x8 v = *(const s16x8*)(ep + row*72 + kq*8);
        *(s16x8*)(C + (size_t)row*MM + kq*8) = v;
    }
}

// ---------------- K8: proj GEMM (bf16 A, fp32 C + bias) ----------------
__global__ __launch_bounds__(256) void k_proj(const short* __restrict__ msum,
                                              const short* __restrict__ WpT,
                                              const float* __restrict__ bp,
                                              float* __restrict__ tmp)
{
    __shared__ char lds[16384];
    const int col0 = blockIdx.x * 128;
    const int row0 = blockIdx.y * 128;
    const char* At = (const char*)(msum + (size_t)row0*MM);
    const char* Bt = (const char*)(WpT + (size_t)col0*MM);
    f32x4 acc[4][4]; zero_acc(acc);
    gemm_core<false>(At, MM, Bt, MM, MM, lds, acc);

    const int tid = threadIdx.x, lane = tid & 63, w = tid >> 6;
    const int wr = w >> 1, wc = w & 1;
    float bj[4];
    #pragma unroll
    for (int j = 0; j < 4; ++j) bj[j] = bp[col0 + wc*64 + j*16 + (lane & 15)];
    #pragma unroll
    for (int i = 0; i < 4; ++i)
        #pragma unroll
        for (int r = 0; r < 4; ++r) {
            int grow = row0 + wr*64 + i*16 + (lane >> 4)*4 + r;
            #pragma unroll
            for (int j = 0; j < 4; ++j) {
                int gcol = col0 + wc*64 + j*16 + (lane & 15);
                tmp[(size_t)grow*MM + gcol] = acc[i][j][r] + bj[j];
            }
        }
}

// ---------------- K9: R = relu(anchor_feat + LN(tmp)), bf16 out ----------------
__global__ __launch_bounds__(256) void k_ln2(const float* __restrict__ tmp,
                                             const short* __restrict__ down,
                                             const float* __restrict__ g,
                                             const float* __restrict__ beta,
                                             short* __restrict__ R)
{
    const int row  = blockIdx.x*4 + (threadIdx.x >> 6);
    const int lane = threadIdx.x & 63;
    const float* p = tmp + (size_t)row*MM;
    const short* af = down + (size_t)12*BN*MM + (size_t)row*MM;
    float v[6]; float s = 0.f, s2 = 0.f;
    #pragma unroll
    for (int t = 0; t < 6; ++t) { v[t] = p[lane + t*64]; s += v[t]; s2 += v[t]*v[t]; }
    #pragma unroll
    for (int off = 32; off; off >>= 1) { s += __shfl_xor(s, off); s2 += __shfl_xor(s2, off); }
    float mu  = s * (1.f/MM);
    float inv = rsqrtf(s2 * (1.f/MM) - mu*mu + 1e-5f);
    #pragma unroll
    for (int t = 0; t < 6; ++t) {
        int m = lane + t*64;
        float o = bf2f(af[m]) + (v[t]-mu)*inv * g[m] + beta[m];
        R[(size_t)row*MM + m] = f2bf(fmaxf(o, 0.f));
    }
}

// ---------------- K10: up GEMM (bf16 A, fp32 C + bias) -> d_out ----------------
__global__ __launch_bounds__(256) void k_up(const short* __restrict__ R,
                                            const short* __restrict__ WuT,
                                            const float* __restrict__ bu,
                                            float* __restrict__ Y)
{
    __shared__ char lds[16384];
    const int col0 = blockIdx.x * 128;
    const int row0 = blockIdx.y * 128;
    const char* At = (const char*)(R + (size_t)row0*MM);
    const char* Bt = (const char*)(WuT + (size_t)col0*MM);
    f32x4 acc[4][4]; zero_acc(acc);
    gemm_core<false>(At, MM, Bt, MM, MM, lds, acc);

    const int tid = threadIdx.x, lane = tid & 63, w = tid >> 6;
    const int wr = w >> 1, wc = w & 1;
    float bj[4];
    #pragma unroll
    for (int j = 0; j < 4; ++j) bj[j] = bu[col0 + wc*64 + j*16 + (lane & 15)];
    #pragma unroll
    for (int i = 0; i < 4; ++i)
        #pragma unroll
        for (int r = 0; r < 4; ++r) {
            int grow = row0 + wr*64 + i*16 + (lane >> 4)*4 + r;
            #pragma unroll
            for (int j = 0; j < 4; ++j) {
                int gcol = col0 + wc*64 + j*16 + (lane & 15);
                Y[(size_t)grow*EE + gcol] = acc[i][j][r] + bj[j];
            }
        }
}

// ---------------- K11: lengths tail ----------------
__global__ void k_len(const int* __restrict__ lengths, float* __restrict__ out)
{
    if (threadIdx.x < BB)
        out[(size_t)BB*NN*EE + threadIdx.x] = (float)lengths[threadIdx.x];
}

extern "C" void kernel_launch(void* const* d_in, const int* in_sizes, int n_in,
                              void* d_out, int out_size, void* d_ws, size_t ws_size,
                              hipStream_t stream)
{
    const float* X    = (const float*)d_in[0];
    const int*   len  = (const int*)  d_in[1];
    const float* Wd   = (const float*)d_in[2];
    const float* bd   = (const float*)d_in[3];
    const float* gd   = (const float*)d_in[4];
    const float* betd = (const float*)d_in[5];
    const float* Wp   = (const float*)d_in[6];
    const float* bp   = (const float*)d_in[7];
    const float* gp   = (const float*)d_in[8];
    const float* betp = (const float*)d_in[9];
    const float* Wu   = (const float*)d_in[10];
    const float* bu   = (const float*)d_in[11];
    const float* Wg   = (const float*)d_in[12];
    const float* bg   = (const float*)d_in[13];
    float* out = (float*)d_out;

    // workspace layout
    float* ws     = (float*)d_ws;
    float* tmp    = ws;                          // 6291456 f
    float* t_agg  = tmp + 6291456;               // 147456 f
    float* anchor = t_agg + 147456;              // 12288 f
    float* conf   = anchor + 12288;              // 384 f
    short* down   = (short*)(conf + 384);        // 81788928 sh  [l][b][n][m]
    short* downTb = down   + (size_t)81788928;   // 75497472 sh  [b][m][l][n]
    short* cw     = downTb + (size_t)75497472;   // 100663296 sh [b][n][l*512+k]
    short* msum   = cw     + (size_t)100663296;  // 6291456 sh
    short* R      = msum   + (size_t)6291456;    // 6291456 sh
    short* WdT    = R      + (size_t)6291456;    // 3833856 sh
    short* WpT    = WdT    + (size_t)3833856;    // 147456 sh
    short* WuT    = WpT    + (size_t)147456;     // 294912 sh

    // 0) weight transposes -> bf16
    k_wt<<<dim3(6, 12, 13), 256, 0, stream>>>(Wd, WdT, HH, MM, (size_t)HH*MM, (size_t)HH*MM);
    k_wt<<<dim3(6, 6, 1),   256, 0, stream>>>(Wp, WpT, MM, MM, 0, 0);
    k_wt<<<dim3(12, 6, 1),  256, 0, stream>>>(Wu, WuT, MM, EE, 0, 0);
    // 1) down GEMM (pre-LN bf16)
    k_down<<<dim3(MM/128, BN/128, LL), 256, 0, stream>>>(X, WdT, bd, down);
    // 2) LN in place + transposed copy
    k_ln<<<LL*BB*8, 256, 0, stream>>>(down, gd, betd, downTb);
    // 3) masked means
    k_agg<<<dim3(BB, LL), 384, 0, stream>>>(down, len, t_agg, anchor);
    // 4) conf
    k_conf<<<BB, 64, 0, stream>>>(anchor, t_agg, Wg, bg, conf);
    // 5) S for all (b,l) -> cw
    k_s<<<dim3(NN/128, NN/128, BB*12), 256, 0, stream>>>(down, len, cw);
    // 6) normalize rows + fold conf + identity
    k_norm<<<(BB*12*NN)/4, 256, 0, stream>>>(cw, conf);
    // 7) single big-K merge -> msum (bf16)
    k_merge<<<dim3(MM/128, NN/128, BB), 256, 0, stream>>>(cw, downTb, msum);
    // 8) proj
    k_proj<<<dim3(MM/128, BN/128), 256, 0, stream>>>(msum, WpT, bp, tmp);
    // 9) residual + LN + relu -> bf16
    k_ln2<<<BN/4, 256, 0, stream>>>(tmp, down, gp, betp, R);
    // 10) up -> out
    k_up<<<dim3(EE/128, BN/128), 256, 0, stream>>>(R, WuT, bu, out);
    // 11) lengths tail
    k_len<<<1, 64, 0, stream>>>(len, out);
}

// Round 4
// 1073.688 us; speedup vs baseline: 4.1856x; 1.0987x over previous
//
#include <hip/hip_runtime.h>

#define LL 13
#define BB 32
#define NN 512
#define HH 768
#define MM 384
#define EE 768
#define BN (BB*NN)   // 16384
#define K12 (12*NN)  // 6144

typedef __attribute__((ext_vector_type(8))) short s16x8;
typedef __attribute__((ext_vector_type(4))) float f32x4;
typedef unsigned int u32;
#define AS1 __attribute__((address_space(1)))
#define AS3 __attribute__((address_space(3)))

__device__ __forceinline__ short f2bf(float f) {
    union { float f; u32 u; } c; c.f = f;
    u32 u = c.u;
    return (short)((u + 0x7fffu + ((u >> 16) & 1u)) >> 16);   // RNE
}
__device__ __forceinline__ float bf2f(short h) {
    union { u32 u; float f; } c; c.u = ((u32)(unsigned short)h) << 16;
    return c.f;
}
__device__ __forceinline__ void gload16(const void* g, void* l) {
    __builtin_amdgcn_global_load_lds((const AS1 u32*)g, (AS3 u32*)l, 16, 0, 0);
}

// ============ bf16 MFMA GEMM core: 128x128 tile, BK=32, 4 waves, 16x16x32 ============
// C(128x128) = A(128xK) * B^T(128xK), both operands reduction-contiguous.
// 2-phase double-buffered pipeline: stage K-step t+1 while computing t; ONE barrier/step.
// LDS: buf0 @0 (A 8K, B 8K), buf1 @16384. Slots: base + g*1024 + lane*16.
template<bool AFP32>
__device__ __forceinline__ void gemm_core(const char* At, int lda,
                                          const char* Bt, int ldb,
                                          int K, char* lds, f32x4 acc[4][4])
{
    const int tid  = threadIdx.x;
    const int lane = tid & 63;
    const int w    = tid >> 6;
    const int mt0 = (w >> 1) * 4;
    const int nt0 = (w & 1) * 4;

    const int rg0 = (w*2)*16 + (lane & 15);
    const int rg1 = rg0 + 16;
    const int kcb = (lane >> 4) * 16;
    const char* gb0 = Bt + (size_t)rg0 * ldb * 2 + kcb;
    const char* gb1 = Bt + (size_t)rg1 * ldb * 2 + kcb;
    const int lboff0 = 8192 + (w*2)*1024;
    const int lboff1 = lboff0 + 1024;

    auto mfma_step = [&](int bo) {
        s16x8 af[4], bf4[4];
        char* sA = lds + bo;
        char* sB = sA + 8192;
        #pragma unroll
        for (int i = 0; i < 4; ++i) af[i] = *(const s16x8*)(sA + ((mt0+i)<<10) + lane*16);
        #pragma unroll
        for (int j = 0; j < 4; ++j) bf4[j] = *(const s16x8*)(sB + ((nt0+j)<<10) + lane*16);
        #pragma unroll
        for (int i = 0; i < 4; ++i)
            #pragma unroll
            for (int j = 0; j < 4; ++j)
                acc[i][j] = __builtin_amdgcn_mfma_f32_16x16x32_bf16(af[i], bf4[j], acc[i][j], 0, 0, 0);
    };

    if (!AFP32) {
        const char* ga0 = At + (size_t)rg0 * lda * 2 + kcb;
        const char* ga1 = At + (size_t)rg1 * lda * 2 + kcb;
        const int laoff0 = (w*2)*1024, laoff1 = laoff0 + 1024;
        // prologue: stage t0 into buf0
        gload16(ga0, lds + laoff0); gload16(ga1, lds + laoff1);
        gload16(gb0, lds + lboff0); gload16(gb1, lds + lboff1);
        ga0 += 64; ga1 += 64; gb0 += 64; gb1 += 64;
        __syncthreads();
        int bo = 0;
        for (int k0 = 32; k0 < K; k0 += 32) {
            const int nbo = bo ^ 16384;
            gload16(ga0, lds + nbo + laoff0); gload16(ga1, lds + nbo + laoff1);
            gload16(gb0, lds + nbo + lboff0); gload16(gb1, lds + nbo + lboff1);
            ga0 += 64; ga1 += 64; gb0 += 64; gb1 += 64;
            mfma_step(bo);
            __syncthreads();
            bo = nbo;
        }
        mfma_step(bo);
    } else {
        // A fp32 tile: 128 rows x 32 k = 1024 x 16B chunks; instr c: id=c*256+tid
        // global fully coalesced (1KB/instr); lds slot ((row>>4)*64+(row&15)+(c16>>1)*16)*16+(c16&1)*8
        size_t goff_[4]; int loff_[4];
        #pragma unroll
        for (int c = 0; c < 4; ++c) {
            int id = c*256 + tid;
            int row = id >> 3, c16 = id & 7;
            goff_[c] = (size_t)row * lda * 4 + c16 * 16;
            loff_[c] = ((row>>4)*64 + (row&15) + (c16>>1)*16)*16 + (c16&1)*8;
        }
        f32x4 g[4];
        #pragma unroll
        for (int c = 0; c < 4; ++c) g[c] = *(const f32x4*)(At + goff_[c]);
        gload16(gb0, lds + lboff0); gload16(gb1, lds + lboff1);
        gb0 += 64; gb1 += 64;
        #pragma unroll
        for (int c = 0; c < 4; ++c) {
            u32 p0 = ((u32)(unsigned short)f2bf(g[c][0])) | (((u32)(unsigned short)f2bf(g[c][1])) << 16);
            u32 p1 = ((u32)(unsigned short)f2bf(g[c][2])) | (((u32)(unsigned short)f2bf(g[c][3])) << 16);
            u32* d = (u32*)(lds + loff_[c]);
            d[0] = p0; d[1] = p1;
        }
        __syncthreads();
        int bo = 0;
        size_t kb = 128;
        for (int k0 = 32; k0 < K; k0 += 32, kb += 128) {
            const int nbo = bo ^ 16384;
            #pragma unroll
            for (int c = 0; c < 4; ++c) g[c] = *(const f32x4*)(At + goff_[c] + kb);
            gload16(gb0, lds + nbo + lboff0); gload16(gb1, lds + nbo + lboff1);
            gb0 += 64; gb1 += 64;
            mfma_step(bo);
            #pragma unroll
            for (int c = 0; c < 4; ++c) {
                u32 p0 = ((u32)(unsigned short)f2bf(g[c][0])) | (((u32)(unsigned short)f2bf(g[c][1])) << 16);
                u32 p1 = ((u32)(unsigned short)f2bf(g[c][2])) | (((u32)(unsigned short)f2bf(g[c][3])) << 16);
                u32* d = (u32*)(lds + nbo + loff_[c]);
                d[0] = p0; d[1] = p1;
            }
            __syncthreads();
            bo = nbo;
        }
        mfma_step(bo);
    }
}

__device__ __forceinline__ void zero_acc(f32x4 acc[4][4]) {
    #pragma unroll
    for (int i = 0; i < 4; ++i)
        #pragma unroll
        for (int j = 0; j < 4; ++j) {
            acc[i][j][0] = 0.f; acc[i][j][1] = 0.f;
            acc[i][j][2] = 0.f; acc[i][j][3] = 0.f;
        }
}

// ---------------- K0: weight transpose fp32[R][C] -> bf16[C][R] ----------------
__global__ __launch_bounds__(256) void k_wt(const float* __restrict__ in, short* __restrict__ out,
                                            int R, int C, size_t zin, size_t zout)
{
    __shared__ short L[64][80];
    const float* I = in + (size_t)blockIdx.z * zin;
    short* O = out + (size_t)blockIdx.z * zout;
    const int r0 = blockIdx.y * 64, c0 = blockIdx.x * 64;
    const int t = threadIdx.x;
    {
        int r = t >> 2, cq = (t & 3) * 16;
        const float* p = I + (size_t)(r0 + r) * C + c0 + cq;
        s16x8 a, b;
        f32x4 u0 = *(const f32x4*)(p);
        f32x4 u1 = *(const f32x4*)(p + 4);
        f32x4 u2 = *(const f32x4*)(p + 8);
        f32x4 u3 = *(const f32x4*)(p + 12);
        a[0]=f2bf(u0[0]); a[1]=f2bf(u0[1]); a[2]=f2bf(u0[2]); a[3]=f2bf(u0[3]);
        a[4]=f2bf(u1[0]); a[5]=f2bf(u1[1]); a[6]=f2bf(u1[2]); a[7]=f2bf(u1[3]);
        b[0]=f2bf(u2[0]); b[1]=f2bf(u2[1]); b[2]=f2bf(u2[2]); b[3]=f2bf(u2[3]);
        b[4]=f2bf(u3[0]); b[5]=f2bf(u3[1]); b[6]=f2bf(u3[2]); b[7]=f2bf(u3[3]);
        *(s16x8*)&L[r][cq]     = a;
        *(s16x8*)&L[r][cq + 8] = b;
    }
    __syncthreads();
    #pragma unroll
    for (int it = 0; it < 2; ++it) {
        int id = it * 256 + t;
        int cc = id >> 3, rq = id & 7;
        s16x8 v;
        #pragma unroll
        for (int e = 0; e < 8; ++e) v[e] = L[rq*8 + e][cc];
        *(s16x8*)(O + (size_t)(c0 + cc) * R + r0 + rq*8) = v;
    }
}

// ---------------- K1: down GEMM (fp32 A, +bias, bf16 out pre-LN) ----------------
__global__ __launch_bounds__(256) void k_down(const float* __restrict__ X,
                                              const short* __restrict__ WdT,
                                              const float* __restrict__ bd,
                                              short* __restrict__ down)
{
    __shared__ char lds[36864];
    const int lg = ((blockIdx.x & 7) * 624) + (blockIdx.x >> 3);   // XCD-chunked swizzle
    const int col0 = (lg % 3) * 128;
    const int row0 = ((lg / 3) & 127) * 128;
    const int l = lg / 384;
    const char* At = (const char*)(X   + (size_t)l*BN*HH + (size_t)row0*HH);
    const char* Bt = (const char*)(WdT + (size_t)l*MM*HH + (size_t)col0*HH);
    f32x4 acc[4][4]; zero_acc(acc);
    gemm_core<true>(At, HH, Bt, HH, HH, lds, acc);

    const int tid = threadIdx.x, lane = tid & 63, w = tid >> 6;
    const int wr = w >> 1, wc = w & 1;
    float bj[4];
    #pragma unroll
    for (int j = 0; j < 4; ++j) bj[j] = bd[l*MM + col0 + wc*64 + j*16 + (lane & 15)];
    __syncthreads();
    short* ep = (short*)(lds + w * 9216);
    #pragma unroll
    for (int i = 0; i < 4; ++i) {
        int rr = i*16 + (lane >> 4) * 4;
        #pragma unroll
        for (int j = 0; j < 4; ++j) {
            int cc = j*16 + (lane & 15);
            #pragma unroll
            for (int r = 0; r < 4; ++r)
                ep[(rr + r)*72 + cc] = f2bf(acc[i][j][r] + bj[j]);
        }
    }
    __syncthreads();
    short* C = down + (size_t)l*BN*MM;
    #pragma unroll
    for (int it = 0; it < 8; ++it) {
        int c = it*64 + lane;
        int row = c >> 3, kq = c & 7;
        s16x8 v = *(const s16x8*)(ep + row*72 + kq*8);
        int grow = row0 + wr*64 + row;
        int gcol = col0 + wc*64 + kq*8;
        *(s16x8*)(C + (size_t)grow*MM + gcol) = v;
    }
}

// ---------------- K2: LN in place (bf16) + transposed copy downTb[b][m][l][n] for l<12 ----------------
__global__ __launch_bounds__(256) void k_ln(short* __restrict__ down,
                                            const float* __restrict__ g,
                                            const float* __restrict__ beta,
                                            short* __restrict__ downTb)
{
    __shared__ short Lt[64][392];
    const int blk = blockIdx.x;
    const int l = blk / (BB*8);
    const int rem = blk % (BB*8);
    const int b = rem >> 3;
    const int n0 = (rem & 7) * 64;
    const int tid = threadIdx.x, lane = tid & 63, w = tid >> 6;

    for (int it = 0; it < 16; ++it) {
        int ri = it*4 + w;
        int n = n0 + ri;
        short* p = down + (((size_t)l*BB + b)*NN + n) * MM;
        float v[6]; float s = 0.f, s2 = 0.f;
        #pragma unroll
        for (int t = 0; t < 6; ++t) { v[t] = bf2f(p[lane + t*64]); s += v[t]; s2 += v[t]*v[t]; }
        #pragma unroll
        for (int off = 32; off; off >>= 1) { s += __shfl_xor(s, off); s2 += __shfl_xor(s2, off); }
        float mu  = s * (1.f/MM);
        float inv = rsqrtf(s2 * (1.f/MM) - mu*mu + 1e-5f);
        #pragma unroll
        for (int t = 0; t < 6; ++t) {
            int m = lane + t*64;
            short o = f2bf((v[t]-mu)*inv * g[l*MM + m] + beta[l*MM + m]);
            p[m] = o;
            Lt[ri][m] = o;
        }
    }
    if (l == 12) return;
    __syncthreads();
    short* O = downTb + ((size_t)b*MM*12 + l) * NN;   // + m*12*NN + n
    #pragma unroll
    for (int it = 0; it < 12; ++it) {
        int id = it*256 + tid;
        int m = id >> 3, nq = id & 7;
        s16x8 vv;
        #pragma unroll
        for (int e = 0; e < 8; ++e) vv[e] = Lt[nq*8 + e][m];
        *(s16x8*)(O + (size_t)m*12*NN + n0 + nq*8) = vv;
    }
}

// ---------------- K3: masked means ----------------
__global__ __launch_bounds__(384) void k_agg(const short* __restrict__ down,
                                             const int* __restrict__ lengths,
                                             float* __restrict__ t_agg,
                                             float* __restrict__ anchor)
{
    const int b = blockIdx.x;
    const int l = blockIdx.y;
    const int m = threadIdx.x;
    const int len = lengths[b];
    const short* p = down + ((size_t)l*BB + b)*NN*MM;
    float s = 0.f;
    for (int n = 0; n < len; ++n) s += bf2f(p[(size_t)n*MM + m]);
    s /= (float)len;
    if (l == 12) anchor[b*MM + m] = s;
    else         t_agg[((size_t)l*BB + b)*MM + m] = s;
}

// ---------------- K4: conf ----------------
__global__ __launch_bounds__(64) void k_conf(const float* __restrict__ anchor,
                                             const float* __restrict__ t_agg,
                                             const float* __restrict__ Wg,
                                             const float* __restrict__ bg,
                                             float* __restrict__ conf)
{
    const int b = blockIdx.x;
    const int lane = threadIdx.x;
    float lg[12];
    #pragma unroll
    for (int l = 0; l < 12; ++l) {
        float s = 0.f;
        #pragma unroll
        for (int t = 0; t < 6; ++t) {
            int m = lane + t*64;
            s += anchor[b*MM + m] * t_agg[((size_t)l*BB + b)*MM + m] * Wg[m];
        }
        #pragma unroll
        for (int off = 32; off; off >>= 1) s += __shfl_xor(s, off);
        lg[l] = s + bg[0];
    }
    float mx = lg[0];
    #pragma unroll
    for (int l = 1; l < 12; ++l) mx = fmaxf(mx, lg[l]);
    float den = 0.f, e[12];
    #pragma unroll
    for (int l = 0; l < 12; ++l) { e[l] = expf(lg[l]-mx); den += e[l]; }
    if (lane == 0) {
        #pragma unroll
        for (int l = 0; l < 12; ++l) conf[b*12 + l] = e[l]/den;
    }
}

// ---------------- K5: S = anchor_feat @ targets^T (relu, col-mask) -> cw[b][n][l*512+k] ----------------
__global__ __launch_bounds__(256) void k_s(const short* __restrict__ down,
                                           const int* __restrict__ lengths,
                                           short* __restrict__ cw)
{
    __shared__ char lds[36864];
    const int lg = ((blockIdx.x & 7) * 768) + (blockIdx.x >> 3);   // XCD-chunked swizzle
    const int col0 = (lg & 3) * 128;
    const int row0 = ((lg >> 2) & 3) * 128;
    const int z = lg >> 4;
    const int b = z / 12;
    const int l = z % 12;
    const char* At = (const char*)(down + ((size_t)12*BB + b)*NN*MM + (size_t)row0*MM);
    const char* Bt = (const char*)(down + ((size_t)l*BB  + b)*NN*MM + (size_t)col0*MM);
    f32x4 acc[4][4]; zero_acc(acc);
    gemm_core<false>(At, MM, Bt, MM, MM, lds, acc);

    const int tid = threadIdx.x, lane = tid & 63, w = tid >> 6;
    const int wr = w >> 1, wc = w & 1;
    const int len = lengths[b];
    __syncthreads();
    short* ep = (short*)(lds + w * 9216);
    #pragma unroll
    for (int i = 0; i < 4; ++i) {
        int rr = i*16 + (lane >> 4) * 4;
        #pragma unroll
        for (int j = 0; j < 4; ++j) {
            int cc = j*16 + (lane & 15);
            bool keep = (col0 + wc*64 + cc) < len;
            #pragma unroll
            for (int r = 0; r < 4; ++r) {
                float v = keep ? fmaxf(acc[i][j][r], 0.f) : 0.f;
                ep[(rr + r)*72 + cc] = f2bf(v);
            }
        }
    }
    __syncthreads();
    short* C = cw + ((size_t)b*NN + row0 + wr*64)*K12 + (size_t)l*NN + col0 + wc*64;
    #pragma unroll
    for (int it = 0; it < 8; ++it) {
        int c = it*64 + lane;
        int row = c >> 3, kq = c & 7;
        s16x8 v = *(const s16x8*)(ep + row*72 + kq*8);
        *(s16x8*)(C + (size_t)row*K12 + kq*8) = v;
    }
}

// ---------------- K6: normalize cw rows: cw = conf*(cw/(rowsum+eps)), diag += conf ----------------
__global__ __launch_bounds__(256) void k_norm(short* __restrict__ cw,
                                              const float* __restrict__ conf)
{
    const int rid  = blockIdx.x*4 + (threadIdx.x >> 6);
    const int lane = threadIdx.x & 63;
    const int b   = rid / (NN*12);
    const int rem = rid % (NN*12);
    const int n   = rem / 12;
    const int l   = rem % 12;
    short* p = cw + ((size_t)b*NN + n)*K12 + (size_t)l*NN + lane*8;
    s16x8 v = *(const s16x8*)p;
    float f[8]; float s = 0.f;
    #pragma unroll
    for (int e = 0; e < 8; ++e) { f[e] = bf2f(v[e]); s += f[e]; }
    #pragma unroll
    for (int off = 32; off; off >>= 1) s += __shfl_xor(s, off);
    const float cf = conf[b*12 + l];
    const float sc = cf / (s + 1e-8f);
    #pragma unroll
    for (int e = 0; e < 8; ++e) {
        float o = f[e] * sc;
        if (lane*8 + e == n) o += cf;          // identity (+eye) folded in, pre-scaled by conf
        v[e] = f2bf(o);
    }
    *(s16x8*)p = v;
}

// ---------------- K7: msum[b] = cw_norm[b] @ targetsT_all[b], K=6144, bf16 out ----------------
__global__ __launch_bounds__(256) void k_merge(const short* __restrict__ cw,
                                               const short* __restrict__ downTb,
                                               short* __restrict__ msum)
{
    __shared__ char lds[36864];
    const int lg = ((blockIdx.x & 7) * 48) + (blockIdx.x >> 3);    // XCD-chunked swizzle
    const int col0 = (lg % 3) * 128;
    const int row0 = ((lg / 3) & 3) * 128;
    const int b = lg / 12;
    const char* At = (const char*)(cw     + ((size_t)b*NN + row0)*K12);
    const char* Bt = (const char*)(downTb + ((size_t)b*MM + col0)*K12);
    f32x4 acc[4][4]; zero_acc(acc);
    gemm_core<false>(At, K12, Bt, K12, K12, lds, acc);

    const int tid = threadIdx.x, lane = tid & 63, w = tid >> 6;
    const int wr = w >> 1, wc = w & 1;
    __syncthreads();
    short* ep = (short*)(lds + w * 9216);
    #pragma unroll
    for (int i = 0; i < 4; ++i) {
        int rr = i*16 + (lane >> 4) * 4;
        #pragma unroll
        for (int j = 0; j < 4; ++j) {
            int cc = j*16 + (lane & 15);
            #pragma unroll
            for (int r = 0; r < 4; ++r)
                ep[(rr + r)*72 + cc] = f2bf(acc[i][j][r]);
        }
    }
    __syncthreads();
    short* C = msum + ((size_t)b*NN + row0 + wr*64)*MM + col0 + wc*64;
    #pragma unroll
    for (int it = 0; it < 8; ++it) {
        int c = it*64 + lane;
        int row = c >> 3, kq = c & 7;
        s16x8 v = *(const s16x8*)(ep + row*72 + kq*8);
        *(s16x8*)(C + (size_t)row*MM + kq*8) = v;
    }
}

// ---------------- K8: proj GEMM (bf16 A, fp32 C + bias) ----------------
__global__ __launch_bounds__(256) void k_proj(const short* __restrict__ msum,
                                              const short* __restrict__ WpT,
                                              const float* __restrict__ bp,
                                              float* __restrict__ tmp)
{
    __shared__ char lds[32768];
    const int lg = ((blockIdx.x & 7) * 48) + (blockIdx.x >> 3);
    const int col0 = (lg % 3) * 128;
    const int row0 = (lg / 3) * 128;
    const char* At = (const char*)(msum + (size_t)row0*MM);
    const char* Bt = (const char*)(WpT + (size_t)col0*MM);
    f32x4 acc[4][4]; zero_acc(acc);
    gemm_core<false>(At, MM, Bt, MM, MM, lds, acc);

    const int tid = threadIdx.x, lane = tid & 63, w = tid >> 6;
    const int wr = w >> 1, wc = w & 1;
    float bj[4];
    #pragma unroll
    for (int j = 0; j < 4; ++j) bj[j] = bp[col0 + wc*64 + j*16 + (lane & 15)];
    #pragma unroll
    for (int i = 0; i < 4; ++i)
        #pragma unroll
        for (int r = 0; r < 4; ++r) {
            int grow = row0 + wr*64 + i*16 + (lane >> 4)*4 + r;
            #pragma unroll
            for (int j = 0; j < 4; ++j) {
                int gcol = col0 + wc*64 + j*16 + (lane & 15);
                tmp[(size_t)grow*MM + gcol] = acc[i][j][r] + bj[j];
            }
        }
}

// ---------------- K9: R = relu(anchor_feat + LN(tmp)), bf16 out ----------------
__global__ __launch_bounds__(256) void k_ln2(const float* __restrict__ tmp,
                                             const short* __restrict__ down,
                                             const float* __restrict__ g,
                                             const float* __restrict__ beta,
                                             short* __restrict__ R)
{
    const int row  = blockIdx.x*4 + (threadIdx.x >> 6);
    const int lane = threadIdx.x & 63;
    const float* p = tmp + (size_t)row*MM;
    const short* af = down + (size_t)12*BN*MM + (size_t)row*MM;
    float v[6]; float s = 0.f, s2 = 0.f;
    #pragma unroll
    for (int t = 0; t < 6; ++t) { v[t] = p[lane + t*64]; s += v[t]; s2 += v[t]*v[t]; }
    #pragma unroll
    for (int off = 32; off; off >>= 1) { s += __shfl_xor(s, off); s2 += __shfl_xor(s2, off); }
    float mu  = s * (1.f/MM);
    float inv = rsqrtf(s2 * (1.f/MM) - mu*mu + 1e-5f);
    #pragma unroll
    for (int t = 0; t < 6; ++t) {
        int m = lane + t*64;
        float o = bf2f(af[m]) + (v[t]-mu)*inv * g[m] + beta[m];
        R[(size_t)row*MM + m] = f2bf(fmaxf(o, 0.f));
    }
}

// ---------------- K10: up GEMM (bf16 A, fp32 C + bias) -> d_out ----------------
__global__ __launch_bounds__(256) void k_up(const short* __restrict__ R,
                                            const short* __restrict__ WuT,
                                            const float* __restrict__ bu,
                                            float* __restrict__ Y)
{
    __shared__ char lds[32768];
    const int lg = ((blockIdx.x & 7) * 96) + (blockIdx.x >> 3);
    const int col0 = (lg % 6) * 128;
    const int row0 = (lg / 6) * 128;
    const char* At = (const char*)(R + (size_t)row0*MM);
    const char* Bt = (const char*)(WuT + (size_t)col0*MM);
    f32x4 acc[4][4]; zero_acc(acc);
    gemm_core<false>(At, MM, Bt, MM, MM, lds, acc);

    const int tid = threadIdx.x, lane = tid & 63, w = tid >> 6;
    const int wr = w >> 1, wc = w & 1;
    float bj[4];
    #pragma unroll
    for (int j = 0; j < 4; ++j) bj[j] = bu[col0 + wc*64 + j*16 + (lane & 15)];
    #pragma unroll
    for (int i = 0; i < 4; ++i)
        #pragma unroll
        for (int r = 0; r < 4; ++r) {
            int grow = row0 + wr*64 + i*16 + (lane >> 4)*4 + r;
            #pragma unroll
            for (int j = 0; j < 4; ++j) {
                int gcol = col0 + wc*64 + j*16 + (lane & 15);
                Y[(size_t)grow*EE + gcol] = acc[i][j][r] + bj[j];
            }
        }
}

// ---------------- K11: lengths tail ----------------
__global__ void k_len(const int* __restrict__ lengths, float* __restrict__ out)
{
    if (threadIdx.x < BB)
        out[(size_t)BB*NN*EE + threadIdx.x] = (float)lengths[threadIdx.x];
}

extern "C" void kernel_launch(void* const* d_in, const int* in_sizes, int n_in,
                              void* d_out, int out_size, void* d_ws, size_t ws_size,
                              hipStream_t stream)
{
    const float* X    = (const float*)d_in[0];
    const int*   len  = (const int*)  d_in[1];
    const float* Wd   = (const float*)d_in[2];
    const float* bd   = (const float*)d_in[3];
    const float* gd   = (const float*)d_in[4];
    const float* betd = (const float*)d_in[5];
    const float* Wp   = (const float*)d_in[6];
    const float* bp   = (const float*)d_in[7];
    const float* gp   = (const float*)d_in[8];
    const float* betp = (const float*)d_in[9];
    const float* Wu   = (const float*)d_in[10];
    const float* bu   = (const float*)d_in[11];
    const float* Wg   = (const float*)d_in[12];
    const float* bg   = (const float*)d_in[13];
    float* out = (float*)d_out;

    // workspace layout
    float* ws     = (float*)d_ws;
    float* tmp    = ws;                          // 6291456 f
    float* t_agg  = tmp + 6291456;               // 147456 f
    float* anchor = t_agg + 147456;              // 12288 f
    float* conf   = anchor + 12288;              // 384 f
    short* down   = (short*)(conf + 384);        // 81788928 sh  [l][b][n][m]
    short* downTb = down   + (size_t)81788928;   // 75497472 sh  [b][m][l][n]
    short* cw     = downTb + (size_t)75497472;   // 100663296 sh [b][n][l*512+k]
    short* msum   = cw     + (size_t)100663296;  // 6291456 sh
    short* R      = msum   + (size_t)6291456;    // 6291456 sh
    short* WdT    = R      + (size_t)6291456;    // 3833856 sh
    short* WpT    = WdT    + (size_t)3833856;    // 147456 sh
    short* WuT    = WpT    + (size_t)147456;     // 294912 sh

    // 0) weight transposes -> bf16
    k_wt<<<dim3(6, 12, 13), 256, 0, stream>>>(Wd, WdT, HH, MM, (size_t)HH*MM, (size_t)HH*MM);
    k_wt<<<dim3(6, 6, 1),   256, 0, stream>>>(Wp, WpT, MM, MM, 0, 0);
    k_wt<<<dim3(12, 6, 1),  256, 0, stream>>>(Wu, WuT, MM, EE, 0, 0);
    // 1) down GEMM (pre-LN bf16), XCD-swizzled 1D grid
    k_down<<<4992, 256, 0, stream>>>(X, WdT, bd, down);
    // 2) LN in place + transposed copy
    k_ln<<<LL*BB*8, 256, 0, stream>>>(down, gd, betd, downTb);
    // 3) masked means
    k_agg<<<dim3(BB, LL), 384, 0, stream>>>(down, len, t_agg, anchor);
    // 4) conf
    k_conf<<<BB, 64, 0, stream>>>(anchor, t_agg, Wg, bg, conf);
    // 5) S for all (b,l) -> cw
    k_s<<<6144, 256, 0, stream>>>(down, len, cw);
    // 6) normalize rows + fold conf + identity
    k_norm<<<(BB*12*NN)/4, 256, 0, stream>>>(cw, conf);
    // 7) single big-K merge -> msum (bf16)
    k_merge<<<384, 256, 0, stream>>>(cw, downTb, msum);
    // 8) proj
    k_proj<<<384, 256, 0, stream>>>(msum, WpT, bp, tmp);
    // 9) residual + LN + relu -> bf16
    k_ln2<<<BN/4, 256, 0, stream>>>(tmp, down, gp, betp, R);
    // 10) up -> out
    k_up<<<768, 256, 0, stream>>>(R, WuT, bu, out);
    // 11) lengths tail
    k_len<<<1, 64, 0, stream>>>(len, out);
}

// Round 5
// 1067.554 us; speedup vs baseline: 4.2097x; 1.0057x over previous
//
#include <hip/hip_runtime.h>

#define LL 13
#define BB 32
#define NN 512
#define HH 768
#define MM 384
#define EE 768
#define BN (BB*NN)   // 16384
#define K12 (12*NN)  // 6144

typedef __attribute__((ext_vector_type(8))) short s16x8;
typedef __attribute__((ext_vector_type(4))) float f32x4;
typedef __attribute__((ext_vector_type(4))) unsigned int u32x4;
typedef unsigned int u32;
#define AS1 __attribute__((address_space(1)))
#define AS3 __attribute__((address_space(3)))

// hardware packed fp32->bf16 (RNE), gfx950
__device__ __forceinline__ u32 cvtpk2(float a, float b) {
    u32 r; asm("v_cvt_pk_bf16_f32 %0, %1, %2" : "=v"(r) : "v"(a), "v"(b));
    return r;
}
__device__ __forceinline__ short f2bf_hw(float f) {
    u32 r; asm("v_cvt_pk_bf16_f32 %0, %1, %2" : "=v"(r) : "v"(f), "v"(f));
    return (short)r;
}
__device__ __forceinline__ float bf2f(short h) {
    union { u32 u; float f; } c; c.u = ((u32)(unsigned short)h) << 16;
    return c.f;
}
__device__ __forceinline__ void gload16(const void* g, void* l) {
    __builtin_amdgcn_global_load_lds((const AS1 u32*)g, (AS3 u32*)l, 16, 0, 0);
}

// ============ bf16 MFMA GEMM core: 128x128 tile, BK=32, 4 waves, 16x16x32 ============
// C(128x128) = A(128xK) * B^T(128xK), both operands reduction-contiguous.
// 2-phase double-buffered pipeline, one barrier per K-step.
template<bool AFP32>
__device__ __forceinline__ void gemm_core(const char* At, int lda,
                                          const char* Bt, int ldb,
                                          int K, char* lds, f32x4 acc[4][4])
{
    const int tid  = threadIdx.x;
    const int lane = tid & 63;
    const int w    = tid >> 6;
    const int mt0 = (w >> 1) * 4;
    const int nt0 = (w & 1) * 4;

    const int rg0 = (w*2)*16 + (lane & 15);
    const int rg1 = rg0 + 16;
    const int kcb = (lane >> 4) * 16;
    const char* gb0 = Bt + (size_t)rg0 * ldb * 2 + kcb;
    const char* gb1 = Bt + (size_t)rg1 * ldb * 2 + kcb;
    const int lboff0 = 8192 + (w*2)*1024;
    const int lboff1 = lboff0 + 1024;

    auto mfma_step = [&](int bo) {
        s16x8 af[4], bf4[4];
        char* sA = lds + bo;
        char* sB = sA + 8192;
        #pragma unroll
        for (int i = 0; i < 4; ++i) af[i] = *(const s16x8*)(sA + ((mt0+i)<<10) + lane*16);
        #pragma unroll
        for (int j = 0; j < 4; ++j) bf4[j] = *(const s16x8*)(sB + ((nt0+j)<<10) + lane*16);
        #pragma unroll
        for (int i = 0; i < 4; ++i)
            #pragma unroll
            for (int j = 0; j < 4; ++j)
                acc[i][j] = __builtin_amdgcn_mfma_f32_16x16x32_bf16(af[i], bf4[j], acc[i][j], 0, 0, 0);
    };

    if (!AFP32) {
        const char* ga0 = At + (size_t)rg0 * lda * 2 + kcb;
        const char* ga1 = At + (size_t)rg1 * lda * 2 + kcb;
        const int laoff0 = (w*2)*1024, laoff1 = laoff0 + 1024;
        gload16(ga0, lds + laoff0); gload16(ga1, lds + laoff1);
        gload16(gb0, lds + lboff0); gload16(gb1, lds + lboff1);
        ga0 += 64; ga1 += 64; gb0 += 64; gb1 += 64;
        __syncthreads();
        int bo = 0;
        for (int k0 = 32; k0 < K; k0 += 32) {
            const int nbo = bo ^ 16384;
            gload16(ga0, lds + nbo + laoff0); gload16(ga1, lds + nbo + laoff1);
            gload16(gb0, lds + nbo + lboff0); gload16(gb1, lds + nbo + lboff1);
            ga0 += 64; ga1 += 64; gb0 += 64; gb1 += 64;
            mfma_step(bo);
            __syncthreads();
            bo = nbo;
        }
        mfma_step(bo);
    } else {
        size_t goff_[4]; int loff_[4];
        #pragma unroll
        for (int c = 0; c < 4; ++c) {
            int id = c*256 + tid;
            int row = id >> 3, c16 = id & 7;
            goff_[c] = (size_t)row * lda * 4 + c16 * 16;
            loff_[c] = ((row>>4)*64 + (row&15) + (c16>>1)*16)*16 + (c16&1)*8;
        }
        f32x4 g[4];
        #pragma unroll
        for (int c = 0; c < 4; ++c) g[c] = *(const f32x4*)(At + goff_[c]);
        gload16(gb0, lds + lboff0); gload16(gb1, lds + lboff1);
        gb0 += 64; gb1 += 64;
        #pragma unroll
        for (int c = 0; c < 4; ++c) {
            u32* d = (u32*)(lds + loff_[c]);
            d[0] = cvtpk2(g[c][0], g[c][1]);
            d[1] = cvtpk2(g[c][2], g[c][3]);
        }
        __syncthreads();
        int bo = 0;
        size_t kb = 128;
        for (int k0 = 32; k0 < K; k0 += 32, kb += 128) {
            const int nbo = bo ^ 16384;
            #pragma unroll
            for (int c = 0; c < 4; ++c) g[c] = *(const f32x4*)(At + goff_[c] + kb);
            gload16(gb0, lds + nbo + lboff0); gload16(gb1, lds + nbo + lboff1);
            gb0 += 64; gb1 += 64;
            mfma_step(bo);
            #pragma unroll
            for (int c = 0; c < 4; ++c) {
                u32* d = (u32*)(lds + nbo + loff_[c]);
                d[0] = cvtpk2(g[c][0], g[c][1]);
                d[1] = cvtpk2(g[c][2], g[c][3]);
            }
            __syncthreads();
            bo = nbo;
        }
        mfma_step(bo);
    }
}

__device__ __forceinline__ void zero_acc(f32x4 acc[4][4]) {
    #pragma unroll
    for (int i = 0; i < 4; ++i)
        #pragma unroll
        for (int j = 0; j < 4; ++j) {
            acc[i][j][0] = 0.f; acc[i][j][1] = 0.f;
            acc[i][j][2] = 0.f; acc[i][j][3] = 0.f;
        }
}

// ---------------- K0: weight transpose fp32[R][C] -> bf16[C][R] ----------------
__global__ __launch_bounds__(256) void k_wt(const float* __restrict__ in, short* __restrict__ out,
                                            int R, int C, size_t zin, size_t zout)
{
    __shared__ short L[64][80];
    const float* I = in + (size_t)blockIdx.z * zin;
    short* O = out + (size_t)blockIdx.z * zout;
    const int r0 = blockIdx.y * 64, c0 = blockIdx.x * 64;
    const int t = threadIdx.x;
    {
        int r = t >> 2, cq = (t & 3) * 16;
        const float* p = I + (size_t)(r0 + r) * C + c0 + cq;
        f32x4 u0 = *(const f32x4*)(p);
        f32x4 u1 = *(const f32x4*)(p + 4);
        f32x4 u2 = *(const f32x4*)(p + 8);
        f32x4 u3 = *(const f32x4*)(p + 12);
        u32x4 pa, pb;
        pa[0]=cvtpk2(u0[0],u0[1]); pa[1]=cvtpk2(u0[2],u0[3]);
        pa[2]=cvtpk2(u1[0],u1[1]); pa[3]=cvtpk2(u1[2],u1[3]);
        pb[0]=cvtpk2(u2[0],u2[1]); pb[1]=cvtpk2(u2[2],u2[3]);
        pb[2]=cvtpk2(u3[0],u3[1]); pb[3]=cvtpk2(u3[2],u3[3]);
        *(u32x4*)&L[r][cq]     = pa;
        *(u32x4*)&L[r][cq + 8] = pb;
    }
    __syncthreads();
    #pragma unroll
    for (int it = 0; it < 2; ++it) {
        int id = it * 256 + t;
        int cc = id >> 3, rq = id & 7;
        s16x8 v;
        #pragma unroll
        for (int e = 0; e < 8; ++e) v[e] = L[rq*8 + e][cc];
        *(s16x8*)(O + (size_t)(c0 + cc) * R + r0 + rq*8) = v;
    }
}

// ---------------- K1: down GEMM (fp32 A, +bias, bf16 out pre-LN) ----------------
__global__ __launch_bounds__(256) void k_down(const float* __restrict__ X,
                                              const short* __restrict__ WdT,
                                              const float* __restrict__ bd,
                                              short* __restrict__ down)
{
    __shared__ char lds[36864];
    const int lg = ((blockIdx.x & 7) * 624) + (blockIdx.x >> 3);   // XCD-chunked swizzle
    const int col0 = (lg % 3) * 128;
    const int row0 = ((lg / 3) & 127) * 128;
    const int l = lg / 384;
    const char* At = (const char*)(X   + (size_t)l*BN*HH + (size_t)row0*HH);
    const char* Bt = (const char*)(WdT + (size_t)l*MM*HH + (size_t)col0*HH);
    f32x4 acc[4][4]; zero_acc(acc);
    gemm_core<true>(At, HH, Bt, HH, HH, lds, acc);

    const int tid = threadIdx.x, lane = tid & 63, w = tid >> 6;
    const int wr = w >> 1, wc = w & 1;
    float bj[4];
    #pragma unroll
    for (int j = 0; j < 4; ++j) bj[j] = bd[l*MM + col0 + wc*64 + j*16 + (lane & 15)];
    __syncthreads();
    short* ep = (short*)(lds + w * 9216);
    #pragma unroll
    for (int i = 0; i < 4; ++i) {
        int rr = i*16 + (lane >> 4) * 4;
        #pragma unroll
        for (int j = 0; j < 4; ++j) {
            int cc = j*16 + (lane & 15);
            #pragma unroll
            for (int r = 0; r < 4; ++r)
                ep[(rr + r)*72 + cc] = f2bf_hw(acc[i][j][r] + bj[j]);
        }
    }
    __syncthreads();
    short* C = down + (size_t)l*BN*MM;
    #pragma unroll
    for (int it = 0; it < 8; ++it) {
        int c = it*64 + lane;
        int row = c >> 3, kq = c & 7;
        s16x8 v = *(const s16x8*)(ep + row*72 + kq*8);
        int grow = row0 + wr*64 + row;
        int gcol = col0 + wc*64 + kq*8;
        *(s16x8*)(C + (size_t)grow*MM + gcol) = v;
    }
}

// ---------------- K2: LN in place (bf16, packed u32 IO) + transposed copy ----------------
__global__ __launch_bounds__(256) void k_ln(short* __restrict__ down,
                                            const float* __restrict__ g,
                                            const float* __restrict__ beta,
                                            short* __restrict__ downTb)
{
    __shared__ short Lt[64][392];
    const int blk = blockIdx.x;
    const int l = blk / (BB*8);
    const int rem = blk % (BB*8);
    const int b = rem >> 3;
    const int n0 = (rem & 7) * 64;
    const int tid = threadIdx.x, lane = tid & 63, w = tid >> 6;

    for (int it = 0; it < 16; ++it) {
        int ri = it*4 + w;
        int n = n0 + ri;
        short* p = down + (((size_t)l*BB + b)*NN + n) * MM;
        u32* pu = (u32*)p;
        float f[6]; float s = 0.f, s2 = 0.f;
        #pragma unroll
        for (int t = 0; t < 3; ++t) {
            u32 q = pu[lane + t*64];
            float lo = bf2f((short)(q & 0xffff));
            float hi = bf2f((short)(q >> 16));
            f[2*t] = lo; f[2*t+1] = hi;
            s += lo + hi; s2 += lo*lo + hi*hi;
        }
        #pragma unroll
        for (int off = 32; off; off >>= 1) { s += __shfl_xor(s, off); s2 += __shfl_xor(s2, off); }
        float mu  = s * (1.f/MM);
        float inv = rsqrtf(s2 * (1.f/MM) - mu*mu + 1e-5f);
        #pragma unroll
        for (int t = 0; t < 3; ++t) {
            int m0 = (lane + t*64) * 2;
            float o0 = (f[2*t]  -mu)*inv * g[l*MM + m0]     + beta[l*MM + m0];
            float o1 = (f[2*t+1]-mu)*inv * g[l*MM + m0 + 1] + beta[l*MM + m0 + 1];
            u32 pk = cvtpk2(o0, o1);
            pu[lane + t*64] = pk;
            ((u32*)&Lt[ri][0])[lane + t*64] = pk;
        }
    }
    if (l == 12) return;
    __syncthreads();
    short* O = downTb + ((size_t)b*MM*12 + l) * NN;   // + m*12*NN + n
    #pragma unroll
    for (int it = 0; it < 12; ++it) {
        int id = it*256 + tid;
        int m = id >> 3, nq = id & 7;
        s16x8 vv;
        #pragma unroll
        for (int e = 0; e < 8; ++e) vv[e] = Lt[nq*8 + e][m];
        *(s16x8*)(O + (size_t)m*12*NN + n0 + nq*8) = vv;
    }
}

// ---------------- K3: masked means (192 thr, u32 columns) ----------------
__global__ __launch_bounds__(192) void k_agg(const short* __restrict__ down,
                                             const int* __restrict__ lengths,
                                             float* __restrict__ t_agg,
                                             float* __restrict__ anchor)
{
    const int b = blockIdx.x;
    const int l = blockIdx.y;
    const int c = threadIdx.x;           // 0..191, covers columns 2c, 2c+1
    const int len = lengths[b];
    const u32* base = (const u32*)(down + ((size_t)l*BB + b)*NN*MM);
    float s0 = 0.f, s1 = 0.f;
    for (int n = 0; n < len; ++n) {
        u32 q = base[(size_t)n*192 + c];
        s0 += bf2f((short)(q & 0xffff));
        s1 += bf2f((short)(q >> 16));
    }
    float inv = 1.f / (float)len;
    s0 *= inv; s1 *= inv;
    float* dst = (l == 12) ? (anchor + b*MM) : (t_agg + ((size_t)l*BB + b)*MM);
    dst[2*c]   = s0;
    dst[2*c+1] = s1;
}

// ---------------- K4: conf ----------------
__global__ __launch_bounds__(64) void k_conf(const float* __restrict__ anchor,
                                             const float* __restrict__ t_agg,
                                             const float* __restrict__ Wg,
                                             const float* __restrict__ bg,
                                             float* __restrict__ conf)
{
    const int b = blockIdx.x;
    const int lane = threadIdx.x;
    float lg[12];
    #pragma unroll
    for (int l = 0; l < 12; ++l) {
        float s = 0.f;
        #pragma unroll
        for (int t = 0; t < 6; ++t) {
            int m = lane + t*64;
            s += anchor[b*MM + m] * t_agg[((size_t)l*BB + b)*MM + m] * Wg[m];
        }
        #pragma unroll
        for (int off = 32; off; off >>= 1) s += __shfl_xor(s, off);
        lg[l] = s + bg[0];
    }
    float mx = lg[0];
    #pragma unroll
    for (int l = 1; l < 12; ++l) mx = fmaxf(mx, lg[l]);
    float den = 0.f, e[12];
    #pragma unroll
    for (int l = 0; l < 12; ++l) { e[l] = expf(lg[l]-mx); den += e[l]; }
    if (lane == 0) {
        #pragma unroll
        for (int l = 0; l < 12; ++l) conf[b*12 + l] = e[l]/den;
    }
}

// ---------------- K5: S = anchor_feat @ targets^T (relu, col-mask) -> cw[b][n][l*512+k] ----------------
__global__ __launch_bounds__(256) void k_s(const short* __restrict__ down,
                                           const int* __restrict__ lengths,
                                           short* __restrict__ cw)
{
    __shared__ char lds[36864];
    const int lg = ((blockIdx.x & 7) * 768) + (blockIdx.x >> 3);   // XCD-chunked swizzle
    const int col0 = (lg & 3) * 128;
    const int row0 = ((lg >> 2) & 3) * 128;
    const int z = lg >> 4;
    const int b = z / 12;
    const int l = z % 12;
    const char* At = (const char*)(down + ((size_t)12*BB + b)*NN*MM + (size_t)row0*MM);
    const char* Bt = (const char*)(down + ((size_t)l*BB  + b)*NN*MM + (size_t)col0*MM);
    f32x4 acc[4][4]; zero_acc(acc);
    gemm_core<false>(At, MM, Bt, MM, MM, lds, acc);

    const int tid = threadIdx.x, lane = tid & 63, w = tid >> 6;
    const int wr = w >> 1, wc = w & 1;
    const int len = lengths[b];
    __syncthreads();
    short* ep = (short*)(lds + w * 9216);
    #pragma unroll
    for (int i = 0; i < 4; ++i) {
        int rr = i*16 + (lane >> 4) * 4;
        #pragma unroll
        for (int j = 0; j < 4; ++j) {
            int cc = j*16 + (lane & 15);
            bool keep = (col0 + wc*64 + cc) < len;
            #pragma unroll
            for (int r = 0; r < 4; ++r) {
                float v = keep ? fmaxf(acc[i][j][r], 0.f) : 0.f;
                ep[(rr + r)*72 + cc] = f2bf_hw(v);
            }
        }
    }
    __syncthreads();
    short* C = cw + ((size_t)b*NN + row0 + wr*64)*K12 + (size_t)l*NN + col0 + wc*64;
    #pragma unroll
    for (int it = 0; it < 8; ++it) {
        int c = it*64 + lane;
        int row = c >> 3, kq = c & 7;
        s16x8 v = *(const s16x8*)(ep + row*72 + kq*8);
        *(s16x8*)(C + (size_t)row*K12 + kq*8) = v;
    }
}

// ---------------- K6: normalize cw rows: cw = conf*(cw/(rowsum+eps)), diag += conf ----------------
__global__ __launch_bounds__(256) void k_norm(short* __restrict__ cw,
                                              const float* __restrict__ conf)
{
    const int rid  = blockIdx.x*4 + (threadIdx.x >> 6);
    const int lane = threadIdx.x & 63;
    const int b   = rid / (NN*12);
    const int rem = rid % (NN*12);
    const int n   = rem / 12;
    const int l   = rem % 12;
    short* p = cw + ((size_t)b*NN + n)*K12 + (size_t)l*NN + lane*8;
    s16x8 v = *(const s16x8*)p;
    float f[8]; float s = 0.f;
    #pragma unroll
    for (int e = 0; e < 8; ++e) { f[e] = bf2f(v[e]); s += f[e]; }
    #pragma unroll
    for (int off = 32; off; off >>= 1) s += __shfl_xor(s, off);
    const float cf = conf[b*12 + l];
    const float sc = cf / (s + 1e-8f);
    #pragma unroll
    for (int e = 0; e < 8; ++e) {
        float o = f[e] * sc;
        if (lane*8 + e == n) o += cf;          // identity (+eye) folded in, pre-scaled by conf
        v[e] = f2bf_hw(o);
    }
    *(s16x8*)p = v;
}

// ---------------- K7: split-K merge: msH = cw_norm[b] @ targetsT_all[b] over K-half ----------------
__global__ __launch_bounds__(256) void k_merge(const short* __restrict__ cw,
                                               const short* __restrict__ downTb,
                                               float* __restrict__ msA,
                                               float* __restrict__ msB)
{
    __shared__ char lds[36864];
    const int lg = ((blockIdx.x & 7) * 96) + (blockIdx.x >> 3);    // XCD-chunked swizzle
    const int col0 = (lg % 3) * 128;
    const int row0 = ((lg / 3) & 3) * 128;
    const int bkh = lg / 12;
    const int b  = bkh >> 1;
    const int kh = bkh & 1;
    const char* At = (const char*)(cw     + ((size_t)b*NN + row0)*K12 + kh*3072);
    const char* Bt = (const char*)(downTb + ((size_t)b*MM + col0)*K12 + kh*3072);
    f32x4 acc[4][4]; zero_acc(acc);
    gemm_core<false>(At, K12, Bt, K12, 3072, lds, acc);

    const int tid = threadIdx.x, lane = tid & 63, w = tid >> 6;
    const int wr = w >> 1, wc = w & 1;
    float* msH = kh ? msB : msA;
    #pragma unroll
    for (int i = 0; i < 4; ++i)
        #pragma unroll
        for (int r = 0; r < 4; ++r) {
            int grow = row0 + wr*64 + i*16 + (lane >> 4)*4 + r;
            #pragma unroll
            for (int j = 0; j < 4; ++j) {
                int gcol = col0 + wc*64 + j*16 + (lane & 15);
                msH[((size_t)b*NN + grow)*MM + gcol] = acc[i][j][r];
            }
        }
}

// ---------------- K7b: msum = bf16(msA + msB) ----------------
__global__ __launch_bounds__(256) void k_msum2(const float* __restrict__ msA,
                                               const float* __restrict__ msB,
                                               short* __restrict__ msum)
{
    size_t i8 = ((size_t)blockIdx.x*256 + threadIdx.x) * 8;
    f32x4 a0 = *(const f32x4*)(msA + i8);
    f32x4 a1 = *(const f32x4*)(msA + i8 + 4);
    f32x4 b0 = *(const f32x4*)(msB + i8);
    f32x4 b1 = *(const f32x4*)(msB + i8 + 4);
    u32x4 o;
    o[0] = cvtpk2(a0[0]+b0[0], a0[1]+b0[1]);
    o[1] = cvtpk2(a0[2]+b0[2], a0[3]+b0[3]);
    o[2] = cvtpk2(a1[0]+b1[0], a1[1]+b1[1]);
    o[3] = cvtpk2(a1[2]+b1[2], a1[3]+b1[3]);
    *(u32x4*)(msum + i8) = o;
}

// ---------------- K8: proj GEMM (bf16 A, fp32 C + bias) ----------------
__global__ __launch_bounds__(256) void k_proj(const short* __restrict__ msum,
                                              const short* __restrict__ WpT,
                                              const float* __restrict__ bp,
                                              float* __restrict__ tmp)
{
    __shared__ char lds[32768];
    const int lg = ((blockIdx.x & 7) * 48) + (blockIdx.x >> 3);
    const int col0 = (lg % 3) * 128;
    const int row0 = (lg / 3) * 128;
    const char* At = (const char*)(msum + (size_t)row0*MM);
    const char* Bt = (const char*)(WpT + (size_t)col0*MM);
    f32x4 acc[4][4]; zero_acc(acc);
    gemm_core<false>(At, MM, Bt, MM, MM, lds, acc);

    const int tid = threadIdx.x, lane = tid & 63, w = tid >> 6;
    const int wr = w >> 1, wc = w & 1;
    float bj[4];
    #pragma unroll
    for (int j = 0; j < 4; ++j) bj[j] = bp[col0 + wc*64 + j*16 + (lane & 15)];
    #pragma unroll
    for (int i = 0; i < 4; ++i)
        #pragma unroll
        for (int r = 0; r < 4; ++r) {
            int grow = row0 + wr*64 + i*16 + (lane >> 4)*4 + r;
            #pragma unroll
            for (int j = 0; j < 4; ++j) {
                int gcol = col0 + wc*64 + j*16 + (lane & 15);
                tmp[(size_t)grow*MM + gcol] = acc[i][j][r] + bj[j];
            }
        }
}

// ---------------- K9: R = relu(anchor_feat + LN(tmp)), bf16 out ----------------
__global__ __launch_bounds__(256) void k_ln2(const float* __restrict__ tmp,
                                             const short* __restrict__ down,
                                             const float* __restrict__ g,
                                             const float* __restrict__ beta,
                                             short* __restrict__ R)
{
    const int row  = blockIdx.x*4 + (threadIdx.x >> 6);
    const int lane = threadIdx.x & 63;
    const float* p = tmp + (size_t)row*MM;
    const short* af = down + (size_t)12*BN*MM + (size_t)row*MM;
    float v[6]; float s = 0.f, s2 = 0.f;
    #pragma unroll
    for (int t = 0; t < 6; ++t) { v[t] = p[lane + t*64]; s += v[t]; s2 += v[t]*v[t]; }
    #pragma unroll
    for (int off = 32; off; off >>= 1) { s += __shfl_xor(s, off); s2 += __shfl_xor(s2, off); }
    float mu  = s * (1.f/MM);
    float inv = rsqrtf(s2 * (1.f/MM) - mu*mu + 1e-5f);
    #pragma unroll
    for (int t = 0; t < 6; ++t) {
        int m = lane + t*64;
        float o = bf2f(af[m]) + (v[t]-mu)*inv * g[m] + beta[m];
        R[(size_t)row*MM + m] = f2bf_hw(fmaxf(o, 0.f));
    }
}

// ---------------- K10: up GEMM (bf16 A, fp32 C + bias) -> d_out ----------------
__global__ __launch_bounds__(256) void k_up(const short* __restrict__ R,
                                            const short* __restrict__ WuT,
                                            const float* __restrict__ bu,
                                            float* __restrict__ Y)
{
    __shared__ char lds[32768];
    const int lg = ((blockIdx.x & 7) * 96) + (blockIdx.x >> 3);
    const int col0 = (lg % 6) * 128;
    const int row0 = (lg / 6) * 128;
    const char* At = (const char*)(R + (size_t)row0*MM);
    const char* Bt = (const char*)(WuT + (size_t)col0*MM);
    f32x4 acc[4][4]; zero_acc(acc);
    gemm_core<false>(At, MM, Bt, MM, MM, lds, acc);

    const int tid = threadIdx.x, lane = tid & 63, w = tid >> 6;
    const int wr = w >> 1, wc = w & 1;
    float bj[4];
    #pragma unroll
    for (int j = 0; j < 4; ++j) bj[j] = bu[col0 + wc*64 + j*16 + (lane & 15)];
    #pragma unroll
    for (int i = 0; i < 4; ++i)
        #pragma unroll
        for (int r = 0; r < 4; ++r) {
            int grow = row0 + wr*64 + i*16 + (lane >> 4)*4 + r;
            #pragma unroll
            for (int j = 0; j < 4; ++j) {
                int gcol = col0 + wc*64 + j*16 + (lane & 15);
                Y[(size_t)grow*EE + gcol] = acc[i][j][r] + bj[j];
            }
        }
}

// ---------------- K11: lengths tail ----------------
__global__ void k_len(const int* __restrict__ lengths, float* __restrict__ out)
{
    if (threadIdx.x < BB)
        out[(size_t)BB*NN*EE + threadIdx.x] = (float)lengths[threadIdx.x];
}

extern "C" void kernel_launch(void* const* d_in, const int* in_sizes, int n_in,
                              void* d_out, int out_size, void* d_ws, size_t ws_size,
                              hipStream_t stream)
{
    const float* X    = (const float*)d_in[0];
    const int*   len  = (const int*)  d_in[1];
    const float* Wd   = (const float*)d_in[2];
    const float* bd   = (const float*)d_in[3];
    const float* gd   = (const float*)d_in[4];
    const float* betd = (const float*)d_in[5];
    const float* Wp   = (const float*)d_in[6];
    const float* bp   = (const float*)d_in[7];
    const float* gp   = (const float*)d_in[8];
    const float* betp = (const float*)d_in[9];
    const float* Wu   = (const float*)d_in[10];
    const float* bu   = (const float*)d_in[11];
    const float* Wg   = (const float*)d_in[12];
    const float* bg   = (const float*)d_in[13];
    float* out = (float*)d_out;

    // workspace layout
    float* ws     = (float*)d_ws;
    float* tmp    = ws;                          // 6291456 f
    float* t_agg  = tmp + 6291456;               // 147456 f
    float* anchor = t_agg + 147456;              // 12288 f
    float* conf   = anchor + 12288;              // 384 f
    short* down   = (short*)(conf + 384);        // 81788928 sh  [l][b][n][m]
    short* downTb = down   + (size_t)81788928;   // 75497472 sh  [b][m][l][n]
    short* cw     = downTb + (size_t)75497472;   // 100663296 sh [b][n][l*512+k]
    short* msum   = cw     + (size_t)100663296;  // 6291456 sh
    short* R      = msum   + (size_t)6291456;    // 6291456 sh
    short* WdT    = R      + (size_t)6291456;    // 3833856 sh
    short* WpT    = WdT    + (size_t)3833856;    // 147456 sh
    short* WuT    = WpT    + (size_t)147456;     // 294912 sh
    float* msA    = (float*)(WuT + 294912);      // 6291456 f
    float* msB    = msA + 6291456;               // 6291456 f

    // 0) weight transposes -> bf16
    k_wt<<<dim3(6, 12, 13), 256, 0, stream>>>(Wd, WdT, HH, MM, (size_t)HH*MM, (size_t)HH*MM);
    k_wt<<<dim3(6, 6, 1),   256, 0, stream>>>(Wp, WpT, MM, MM, 0, 0);
    k_wt<<<dim3(12, 6, 1),  256, 0, stream>>>(Wu, WuT, MM, EE, 0, 0);
    // 1) down GEMM (pre-LN bf16), XCD-swizzled 1D grid
    k_down<<<4992, 256, 0, stream>>>(X, WdT, bd, down);
    // 2) LN in place + transposed copy
    k_ln<<<LL*BB*8, 256, 0, stream>>>(down, gd, betd, downTb);
    // 3) masked means
    k_agg<<<dim3(BB, LL), 192, 0, stream>>>(down, len, t_agg, anchor);
    // 4) conf
    k_conf<<<BB, 64, 0, stream>>>(anchor, t_agg, Wg, bg, conf);
    // 5) S for all (b,l) -> cw
    k_s<<<6144, 256, 0, stream>>>(down, len, cw);
    // 6) normalize rows + fold conf + identity
    k_norm<<<(BB*12*NN)/4, 256, 0, stream>>>(cw, conf);
    // 7) split-K merge -> fp32 halves, then combine to bf16 msum
    k_merge<<<768, 256, 0, stream>>>(cw, downTb, msA, msB);
    k_msum2<<<3072, 256, 0, stream>>>(msA, msB, msum);
    // 8) proj
    k_proj<<<384, 256, 0, stream>>>(msum, WpT, bp, tmp);
    // 9) residual + LN + relu -> bf16
    k_ln2<<<BN/4, 256, 0, stream>>>(tmp, down, gp, betp, R);
    // 10) up -> out
    k_up<<<768, 256, 0, stream>>>(R, WuT, bu, out);
    // 11) lengths tail
    k_len<<<1, 64, 0, stream>>>(len, out);
}

// Round 6
// 906.479 us; speedup vs baseline: 4.9577x; 1.1777x over previous
//
#include <hip/hip_runtime.h>

#define LL 13
#define BB 32
#define NN 512
#define HH 768
#define MM 384
#define EE 768
#define BN (BB*NN)   // 16384
#define K12 (12*NN)  // 6144

typedef __attribute__((ext_vector_type(8))) short s16x8;
typedef __attribute__((ext_vector_type(4))) float f32x4;
typedef __attribute__((ext_vector_type(4))) unsigned int u32x4;
typedef unsigned int u32;
#define AS1 __attribute__((address_space(1)))
#define AS3 __attribute__((address_space(3)))

// hardware packed fp32->bf16 (RNE), gfx950
__device__ __forceinline__ u32 cvtpk2(float a, float b) {
    u32 r; asm("v_cvt_pk_bf16_f32 %0, %1, %2" : "=v"(r) : "v"(a), "v"(b));
    return r;
}
__device__ __forceinline__ short f2bf_hw(float f) {
    u32 r; asm("v_cvt_pk_bf16_f32 %0, %1, %2" : "=v"(r) : "v"(f), "v"(f));
    return (short)r;
}
__device__ __forceinline__ float bf2f(short h) {
    union { u32 u; float f; } c; c.u = ((u32)(unsigned short)h) << 16;
    return c.f;
}
__device__ __forceinline__ void gload16(const void* g, void* l) {
    __builtin_amdgcn_global_load_lds((const AS1 u32*)g, (AS3 u32*)l, 16, 0, 0);
}

// ============ bf16 MFMA GEMM core: 128x128 tile, BK=32, 4 waves, 16x16x32 ============
// C(128x128) = A(128xK) * B^T(128xK), both operands reduction-contiguous.
// AM=0: A bf16 via global_load_lds. AM=1: A fp32 reg-staged + cvt. AM=2: A = fp32(At)+fp32(At2).
// 2-phase double-buffered pipeline, one barrier per K-step.
template<int AM>
__device__ __forceinline__ void gemm_core(const char* At, const char* At2, int lda,
                                          const char* Bt, int ldb,
                                          int K, char* lds, f32x4 acc[4][4])
{
    const int tid  = threadIdx.x;
    const int lane = tid & 63;
    const int w    = tid >> 6;
    const int mt0 = (w >> 1) * 4;
    const int nt0 = (w & 1) * 4;

    const int rg0 = (w*2)*16 + (lane & 15);
    const int rg1 = rg0 + 16;
    const int kcb = (lane >> 4) * 16;
    const char* gb0 = Bt + (size_t)rg0 * ldb * 2 + kcb;
    const char* gb1 = Bt + (size_t)rg1 * ldb * 2 + kcb;
    const int lboff0 = 8192 + (w*2)*1024;
    const int lboff1 = lboff0 + 1024;

    auto mfma_step = [&](int bo) {
        s16x8 af[4], bf4[4];
        char* sA = lds + bo;
        char* sB = sA + 8192;
        #pragma unroll
        for (int i = 0; i < 4; ++i) af[i] = *(const s16x8*)(sA + ((mt0+i)<<10) + lane*16);
        #pragma unroll
        for (int j = 0; j < 4; ++j) bf4[j] = *(const s16x8*)(sB + ((nt0+j)<<10) + lane*16);
        #pragma unroll
        for (int i = 0; i < 4; ++i)
            #pragma unroll
            for (int j = 0; j < 4; ++j)
                acc[i][j] = __builtin_amdgcn_mfma_f32_16x16x32_bf16(af[i], bf4[j], acc[i][j], 0, 0, 0);
    };

    if (AM == 0) {
        const char* ga0 = At + (size_t)rg0 * lda * 2 + kcb;
        const char* ga1 = At + (size_t)rg1 * lda * 2 + kcb;
        const int laoff0 = (w*2)*1024, laoff1 = laoff0 + 1024;
        gload16(ga0, lds + laoff0); gload16(ga1, lds + laoff1);
        gload16(gb0, lds + lboff0); gload16(gb1, lds + lboff1);
        ga0 += 64; ga1 += 64; gb0 += 64; gb1 += 64;
        __syncthreads();
        int bo = 0;
        for (int k0 = 32; k0 < K; k0 += 32) {
            const int nbo = bo ^ 16384;
            gload16(ga0, lds + nbo + laoff0); gload16(ga1, lds + nbo + laoff1);
            gload16(gb0, lds + nbo + lboff0); gload16(gb1, lds + nbo + lboff1);
            ga0 += 64; ga1 += 64; gb0 += 64; gb1 += 64;
            mfma_step(bo);
            __syncthreads();
            bo = nbo;
        }
        mfma_step(bo);
    } else {
        size_t goff_[4]; int loff_[4];
        #pragma unroll
        for (int c = 0; c < 4; ++c) {
            int id = c*256 + tid;
            int row = id >> 3, c16 = id & 7;
            goff_[c] = (size_t)row * lda * 4 + c16 * 16;
            loff_[c] = ((row>>4)*64 + (row&15) + (c16>>1)*16)*16 + (c16&1)*8;
        }
        f32x4 g[4];
        #pragma unroll
        for (int c = 0; c < 4; ++c) {
            g[c] = *(const f32x4*)(At + goff_[c]);
            if (AM == 2) {
                f32x4 h = *(const f32x4*)(At2 + goff_[c]);
                g[c][0]+=h[0]; g[c][1]+=h[1]; g[c][2]+=h[2]; g[c][3]+=h[3];
            }
        }
        gload16(gb0, lds + lboff0); gload16(gb1, lds + lboff1);
        gb0 += 64; gb1 += 64;
        #pragma unroll
        for (int c = 0; c < 4; ++c) {
            u32* d = (u32*)(lds + loff_[c]);
            d[0] = cvtpk2(g[c][0], g[c][1]);
            d[1] = cvtpk2(g[c][2], g[c][3]);
        }
        __syncthreads();
        int bo = 0;
        size_t kb = 128;
        for (int k0 = 32; k0 < K; k0 += 32, kb += 128) {
            const int nbo = bo ^ 16384;
            #pragma unroll
            for (int c = 0; c < 4; ++c) {
                g[c] = *(const f32x4*)(At + goff_[c] + kb);
                if (AM == 2) {
                    f32x4 h = *(const f32x4*)(At2 + goff_[c] + kb);
                    g[c][0]+=h[0]; g[c][1]+=h[1]; g[c][2]+=h[2]; g[c][3]+=h[3];
                }
            }
            gload16(gb0, lds + nbo + lboff0); gload16(gb1, lds + nbo + lboff1);
            gb0 += 64; gb1 += 64;
            mfma_step(bo);
            #pragma unroll
            for (int c = 0; c < 4; ++c) {
                u32* d = (u32*)(lds + nbo + loff_[c]);
                d[0] = cvtpk2(g[c][0], g[c][1]);
                d[1] = cvtpk2(g[c][2], g[c][3]);
            }
            __syncthreads();
            bo = nbo;
        }
        mfma_step(bo);
    }
}

__device__ __forceinline__ void zero_acc(f32x4 acc[4][4]) {
    #pragma unroll
    for (int i = 0; i < 4; ++i)
        #pragma unroll
        for (int j = 0; j < 4; ++j) {
            acc[i][j][0] = 0.f; acc[i][j][1] = 0.f;
            acc[i][j][2] = 0.f; acc[i][j][3] = 0.f;
        }
}

// ---------------- K_zero: clear raw-sum accumulators ----------------
__global__ __launch_bounds__(256) void k_zero(float* __restrict__ p, int n4)
{
    int i = blockIdx.x*256 + threadIdx.x;
    if (i < n4) { f32x4 z = {0.f,0.f,0.f,0.f}; ((f32x4*)p)[i] = z; }
}

// ---------------- K0: weight transpose fp32[R][C] -> bf16[C][R] ----------------
__global__ __launch_bounds__(256) void k_wt(const float* __restrict__ in, short* __restrict__ out,
                                            int R, int C, size_t zin, size_t zout)
{
    __shared__ short L[64][80];
    const float* I = in + (size_t)blockIdx.z * zin;
    short* O = out + (size_t)blockIdx.z * zout;
    const int r0 = blockIdx.y * 64, c0 = blockIdx.x * 64;
    const int t = threadIdx.x;
    {
        int r = t >> 2, cq = (t & 3) * 16;
        const float* p = I + (size_t)(r0 + r) * C + c0 + cq;
        f32x4 u0 = *(const f32x4*)(p);
        f32x4 u1 = *(const f32x4*)(p + 4);
        f32x4 u2 = *(const f32x4*)(p + 8);
        f32x4 u3 = *(const f32x4*)(p + 12);
        u32x4 pa, pb;
        pa[0]=cvtpk2(u0[0],u0[1]); pa[1]=cvtpk2(u0[2],u0[3]);
        pa[2]=cvtpk2(u1[0],u1[1]); pa[3]=cvtpk2(u1[2],u1[3]);
        pb[0]=cvtpk2(u2[0],u2[1]); pb[1]=cvtpk2(u2[2],u2[3]);
        pb[2]=cvtpk2(u3[0],u3[1]); pb[3]=cvtpk2(u3[2],u3[3]);
        *(u32x4*)&L[r][cq]     = pa;
        *(u32x4*)&L[r][cq + 8] = pb;
    }
    __syncthreads();
    #pragma unroll
    for (int it = 0; it < 2; ++it) {
        int id = it * 256 + t;
        int cc = id >> 3, rq = id & 7;
        s16x8 v;
        #pragma unroll
        for (int e = 0; e < 8; ++e) v[e] = L[rq*8 + e][cc];
        *(s16x8*)(O + (size_t)(c0 + cc) * R + r0 + rq*8) = v;
    }
}

// ---------------- K1: down GEMM (fp32 A, +bias, bf16 out pre-LN) ----------------
__global__ __launch_bounds__(256) void k_down(const float* __restrict__ X,
                                              const short* __restrict__ WdT,
                                              const float* __restrict__ bd,
                                              short* __restrict__ down)
{
    __shared__ char lds[36864];
    const int lg = ((blockIdx.x & 7) * 624) + (blockIdx.x >> 3);   // XCD-chunked swizzle
    const int col0 = (lg % 3) * 128;
    const int row0 = ((lg / 3) & 127) * 128;
    const int l = lg / 384;
    const char* At = (const char*)(X   + (size_t)l*BN*HH + (size_t)row0*HH);
    const char* Bt = (const char*)(WdT + (size_t)l*MM*HH + (size_t)col0*HH);
    f32x4 acc[4][4]; zero_acc(acc);
    gemm_core<1>(At, nullptr, HH, Bt, HH, HH, lds, acc);

    const int tid = threadIdx.x, lane = tid & 63, w = tid >> 6;
    const int wr = w >> 1, wc = w & 1;
    float bj[4];
    #pragma unroll
    for (int j = 0; j < 4; ++j) bj[j] = bd[l*MM + col0 + wc*64 + j*16 + (lane & 15)];
    __syncthreads();
    short* ep = (short*)(lds + w * 9216);
    #pragma unroll
    for (int i = 0; i < 4; ++i) {
        int rr = i*16 + (lane >> 4) * 4;
        #pragma unroll
        for (int j = 0; j < 4; ++j) {
            int cc = j*16 + (lane & 15);
            #pragma unroll
            for (int r = 0; r < 4; ++r)
                ep[(rr + r)*72 + cc] = f2bf_hw(acc[i][j][r] + bj[j]);
        }
    }
    __syncthreads();
    short* C = down + (size_t)l*BN*MM;
    #pragma unroll
    for (int it = 0; it < 8; ++it) {
        int c = it*64 + lane;
        int row = c >> 3, kq = c & 7;
        s16x8 v = *(const s16x8*)(ep + row*72 + kq*8);
        int grow = row0 + wr*64 + row;
        int gcol = col0 + wc*64 + kq*8;
        *(s16x8*)(C + (size_t)grow*MM + gcol) = v;
    }
}

// ---------------- K2: LN in place + transposed copy + fused masked-mean raw sums ----------------
__global__ __launch_bounds__(256) void k_ln(short* __restrict__ down,
                                            const float* __restrict__ g,
                                            const float* __restrict__ beta,
                                            short* __restrict__ downTb,
                                            const int* __restrict__ lengths,
                                            float* __restrict__ t_raw,
                                            float* __restrict__ a_raw)
{
    __shared__ short Lt[64][392];
    __shared__ float sacc[4][384];
    const int blk = blockIdx.x;
    const int l = blk / (BB*8);
    const int rem = blk % (BB*8);
    const int b = rem >> 3;
    const int n0 = (rem & 7) * 64;
    const int tid = threadIdx.x, lane = tid & 63, w = tid >> 6;
    const int len = lengths[b];
    float racc[6] = {0.f,0.f,0.f,0.f,0.f,0.f};

    for (int it = 0; it < 16; ++it) {
        int ri = it*4 + w;
        int n = n0 + ri;
        short* p = down + (((size_t)l*BB + b)*NN + n) * MM;
        u32* pu = (u32*)p;
        float f[6]; float s = 0.f, s2 = 0.f;
        #pragma unroll
        for (int t = 0; t < 3; ++t) {
            u32 q = pu[lane + t*64];
            float lo = bf2f((short)(q & 0xffff));
            float hi = bf2f((short)(q >> 16));
            f[2*t] = lo; f[2*t+1] = hi;
            s += lo + hi; s2 += lo*lo + hi*hi;
        }
        #pragma unroll
        for (int off = 32; off; off >>= 1) { s += __shfl_xor(s, off); s2 += __shfl_xor(s2, off); }
        float mu  = s * (1.f/MM);
        float inv = rsqrtf(s2 * (1.f/MM) - mu*mu + 1e-5f);
        const bool valid = n < len;
        #pragma unroll
        for (int t = 0; t < 3; ++t) {
            int m0 = (lane + t*64) * 2;
            float o0 = (f[2*t]  -mu)*inv * g[l*MM + m0]     + beta[l*MM + m0];
            float o1 = (f[2*t+1]-mu)*inv * g[l*MM + m0 + 1] + beta[l*MM + m0 + 1];
            u32 pk = cvtpk2(o0, o1);
            pu[lane + t*64] = pk;
            ((u32*)&Lt[ri][0])[lane + t*64] = pk;
            if (valid) { racc[2*t] += o0; racc[2*t+1] += o1; }
        }
    }
    // cross-wave reduce of column partial sums, then one atomicAdd per m
    #pragma unroll
    for (int t = 0; t < 3; ++t) {
        int m0 = (lane + t*64) * 2;
        sacc[w][m0]     = racc[2*t];
        sacc[w][m0 + 1] = racc[2*t+1];
    }
    __syncthreads();
    if (w == 0) {
        float* dst = (l == 12) ? (a_raw + b*MM) : (t_raw + ((size_t)l*BB + b)*MM);
        #pragma unroll
        for (int t = 0; t < 3; ++t) {
            #pragma unroll
            for (int e = 0; e < 2; ++e) {
                int m = (lane + t*64)*2 + e;
                float tot = sacc[0][m] + sacc[1][m] + sacc[2][m] + sacc[3][m];
                atomicAdd(&dst[m], tot);
            }
        }
    }
    if (l == 12) return;
    short* O = downTb + ((size_t)b*MM*12 + l) * NN;   // + m*12*NN + n
    #pragma unroll
    for (int it = 0; it < 12; ++it) {
        int id = it*256 + tid;
        int m = id >> 3, nq = id & 7;
        s16x8 vv;
        #pragma unroll
        for (int e = 0; e < 8; ++e) vv[e] = Lt[nq*8 + e][m];
        *(s16x8*)(O + (size_t)m*12*NN + n0 + nq*8) = vv;
    }
}

// ---------------- K4: conf from raw sums (1/len^2 folded into logits) ----------------
__global__ __launch_bounds__(64) void k_conf(const float* __restrict__ a_raw,
                                             const float* __restrict__ t_raw,
                                             const float* __restrict__ Wg,
                                             const float* __restrict__ bg,
                                             const int* __restrict__ lengths,
                                             float* __restrict__ conf)
{
    const int b = blockIdx.x;
    const int lane = threadIdx.x;
    const float len = (float)lengths[b];
    const float inv2 = 1.f/(len*len);
    float lg[12];
    #pragma unroll
    for (int l = 0; l < 12; ++l) {
        float s = 0.f;
        #pragma unroll
        for (int t = 0; t < 6; ++t) {
            int m = lane + t*64;
            s += a_raw[b*MM + m] * t_raw[((size_t)l*BB + b)*MM + m] * Wg[m];
        }
        #pragma unroll
        for (int off = 32; off; off >>= 1) s += __shfl_xor(s, off);
        lg[l] = s * inv2 + bg[0];
    }
    float mx = lg[0];
    #pragma unroll
    for (int l = 1; l < 12; ++l) mx = fmaxf(mx, lg[l]);
    float den = 0.f, e[12];
    #pragma unroll
    for (int l = 0; l < 12; ++l) { e[l] = expf(lg[l]-mx); den += e[l]; }
    if (lane == 0) {
        #pragma unroll
        for (int l = 0; l < 12; ++l) conf[b*12 + l] = e[l]/den;
    }
}

// ---------------- K5: fused S row-block: S=anchor@targets^T, relu/mask, rowsum,
//                  scale by conf/(sum+eps), +conf on diag, store cw. 512 thr, 8 waves. ----------------
__global__ __launch_bounds__(512) void k_srow(const short* __restrict__ down,
                                              const int* __restrict__ lengths,
                                              const float* __restrict__ conf,
                                              short* __restrict__ cw)
{
    __shared__ char lds[75776];   // 40KB staging (A 8K + B 32K), 73728B epilogue, 2KB rowsums @73728
    const int lg = ((blockIdx.x & 7) * 192) + (blockIdx.x >> 3);   // XCD-chunked swizzle
    const int rowblk = lg & 3;
    const int z = lg >> 2;
    const int l = z % 12;
    const int b = z / 12;
    const int tid = threadIdx.x, lane = tid & 63, w = tid >> 6;
    const int wr = w >> 2, wcg = w & 3;

    const char* Ab = (const char*)(down + (((size_t)12*BB + b)*NN + rowblk*128)*MM);
    const char* Bb = (const char*)(down + ((size_t)l*BB + b)*NN*MM);

    // staging: 40 groups of 1024B (A g=0..7, B g=8..39); wave stages groups w*5..w*5+4
    const char* gp[5]; int lo[5];
    #pragma unroll
    for (int q = 0; q < 5; ++q) {
        int gidx = w*5 + q;
        const char* base = (gidx < 8) ? Ab : Bb;
        int grow = ((gidx < 8) ? gidx : (gidx - 8))*16 + (lane & 15);
        gp[q] = base + (size_t)grow * MM * 2 + (lane >> 4)*16;
        lo[q] = gidx*1024 + lane*16;
    }

    f32x4 acc[4][8];
    #pragma unroll
    for (int i = 0; i < 4; ++i)
        #pragma unroll
        for (int j = 0; j < 8; ++j) { acc[i][j][0]=0.f; acc[i][j][1]=0.f; acc[i][j][2]=0.f; acc[i][j][3]=0.f; }

    for (int k0 = 0; k0 < MM; k0 += 32) {
        __syncthreads();
        #pragma unroll
        for (int q = 0; q < 5; ++q) { gload16(gp[q], lds + lo[q]); gp[q] += 64; }
        __syncthreads();
        s16x8 af[4], bf4[8];
        #pragma unroll
        for (int i = 0; i < 4; ++i) af[i] = *(const s16x8*)(lds + ((wr*4 + i)<<10) + lane*16);
        #pragma unroll
        for (int j = 0; j < 8; ++j) bf4[j] = *(const s16x8*)(lds + ((8 + wcg*8 + j)<<10) + lane*16);
        #pragma unroll
        for (int i = 0; i < 4; ++i)
            #pragma unroll
            for (int j = 0; j < 8; ++j)
                acc[i][j] = __builtin_amdgcn_mfma_f32_16x16x32_bf16(af[i], bf4[j], acc[i][j], 0, 0, 0);
    }

    const int len = lengths[b];
    const float cf = conf[b*12 + l];

    // relu + mask + per-lane rowsum partials
    float ps[4][4];
    #pragma unroll
    for (int i = 0; i < 4; ++i)
        #pragma unroll
        for (int r = 0; r < 4; ++r) ps[i][r] = 0.f;
    #pragma unroll
    for (int i = 0; i < 4; ++i)
        #pragma unroll
        for (int j = 0; j < 8; ++j) {
            int c = wcg*128 + j*16 + (lane & 15);
            bool keep = c < len;
            #pragma unroll
            for (int r = 0; r < 4; ++r) {
                float v = keep ? fmaxf(acc[i][j][r], 0.f) : 0.f;
                acc[i][j][r] = v;
                ps[i][r] += v;
            }
        }
    // reduce across the 16 lanes sharing (lane>>4)
    #pragma unroll
    for (int off = 1; off < 16; off <<= 1)
        #pragma unroll
        for (int i = 0; i < 4; ++i)
            #pragma unroll
            for (int r = 0; r < 4; ++r) ps[i][r] += __shfl_xor(ps[i][r], off);
    float* rs = (float*)(lds + 73728);   // [4 colgroups][128 rows]
    if ((lane & 15) == 0) {
        #pragma unroll
        for (int i = 0; i < 4; ++i)
            #pragma unroll
            for (int r = 0; r < 4; ++r)
                rs[wcg*128 + wr*64 + i*16 + (lane >> 4)*4 + r] = ps[i][r];
    }
    __syncthreads();
    float sc[4][4];
    #pragma unroll
    for (int i = 0; i < 4; ++i)
        #pragma unroll
        for (int r = 0; r < 4; ++r) {
            int row = wr*64 + i*16 + (lane >> 4)*4 + r;
            float tot = rs[row] + rs[128 + row] + rs[256 + row] + rs[384 + row];
            sc[i][r] = cf / (tot + 1e-8f);
        }
    // scale + diag + bf16 + per-wave transpose store
    short* ep = (short*)(lds + w * 9216);
    #pragma unroll
    for (int i = 0; i < 4; ++i)
        #pragma unroll
        for (int j = 0; j < 8; ++j) {
            int cc = j*16 + (lane & 15);
            int cg = wcg*128 + cc;
            #pragma unroll
            for (int r = 0; r < 4; ++r) {
                int rr = i*16 + (lane >> 4)*4 + r;
                float o = acc[i][j][r] * sc[i][r];
                int ng = rowblk*128 + wr*64 + rr;
                if (ng == cg) o += cf;
                ep[rr*72 + cc] = f2bf_hw(o);
            }
        }
    short* C = cw + ((size_t)b*NN + rowblk*128 + wr*64)*K12 + (size_t)l*NN + wcg*128;
    #pragma unroll
    for (int it = 0; it < 8; ++it) {
        int cdx = it*64 + lane;
        int row = cdx >> 3, kq = cdx & 7;
        s16x8 v = *(const s16x8*)(ep + row*72 + kq*8);
        *(s16x8*)(C + (size_t)row*K12 + kq*8) = v;
    }
}

// ---------------- K7: split-K merge: msH = cw_norm[b] @ targetsT_all[b] over K-half ----------------
__global__ __launch_bounds__(256) void k_merge(const short* __restrict__ cw,
                                               const short* __restrict__ downTb,
                                               float* __restrict__ msA,
                                               float* __restrict__ msB)
{
    __shared__ char lds[36864];
    const int lg = ((blockIdx.x & 7) * 96) + (blockIdx.x >> 3);    // XCD-chunked swizzle
    const int col0 = (lg % 3) * 128;
    const int row0 = ((lg / 3) & 3) * 128;
    const int bkh = lg / 12;
    const int b  = bkh >> 1;
    const int kh = bkh & 1;
    const char* At = (const char*)(cw     + ((size_t)b*NN + row0)*K12 + kh*3072);
    const char* Bt = (const char*)(downTb + ((size_t)b*MM + col0)*K12 + kh*3072);
    f32x4 acc[4][4]; zero_acc(acc);
    gemm_core<0>(At, nullptr, K12, Bt, K12, 3072, lds, acc);

    const int tid = threadIdx.x, lane = tid & 63, w = tid >> 6;
    const int wr = w >> 1, wc = w & 1;
    float* msH = kh ? msB : msA;
    #pragma unroll
    for (int i = 0; i < 4; ++i)
        #pragma unroll
        for (int r = 0; r < 4; ++r) {
            int grow = row0 + wr*64 + i*16 + (lane >> 4)*4 + r;
            #pragma unroll
            for (int j = 0; j < 4; ++j) {
                int gcol = col0 + wc*64 + j*16 + (lane & 15);
                msH[((size_t)b*NN + grow)*MM + gcol] = acc[i][j][r];
            }
        }
}

// ---------------- K8: proj GEMM (A = msA+msB fp32 fused, fp32 C + bias) ----------------
__global__ __launch_bounds__(256) void k_proj(const float* __restrict__ msA,
                                              const float* __restrict__ msB,
                                              const short* __restrict__ WpT,
                                              const float* __restrict__ bp,
                                              float* __restrict__ tmp)
{
    __shared__ char lds[36864];
    const int lg = ((blockIdx.x & 7) * 48) + (blockIdx.x >> 3);
    const int col0 = (lg % 3) * 128;
    const int row0 = (lg / 3) * 128;
    const char* At  = (const char*)(msA + (size_t)row0*MM);
    const char* At2 = (const char*)(msB + (size_t)row0*MM);
    const char* Bt  = (const char*)(WpT + (size_t)col0*MM);
    f32x4 acc[4][4]; zero_acc(acc);
    gemm_core<2>(At, At2, MM, Bt, MM, MM, lds, acc);

    const int tid = threadIdx.x, lane = tid & 63, w = tid >> 6;
    const int wr = w >> 1, wc = w & 1;
    float bj[4];
    #pragma unroll
    for (int j = 0; j < 4; ++j) bj[j] = bp[col0 + wc*64 + j*16 + (lane & 15)];
    #pragma unroll
    for (int i = 0; i < 4; ++i)
        #pragma unroll
        for (int r = 0; r < 4; ++r) {
            int grow = row0 + wr*64 + i*16 + (lane >> 4)*4 + r;
            #pragma unroll
            for (int j = 0; j < 4; ++j) {
                int gcol = col0 + wc*64 + j*16 + (lane & 15);
                tmp[(size_t)grow*MM + gcol] = acc[i][j][r] + bj[j];
            }
        }
}

// ---------------- K9: R = relu(anchor_feat + LN(tmp)), bf16 out ----------------
__global__ __launch_bounds__(256) void k_ln2(const float* __restrict__ tmp,
                                             const short* __restrict__ down,
                                             const float* __restrict__ g,
                                             const float* __restrict__ beta,
                                             short* __restrict__ R)
{
    const int row  = blockIdx.x*4 + (threadIdx.x >> 6);
    const int lane = threadIdx.x & 63;
    const float* p = tmp + (size_t)row*MM;
    const short* af = down + (size_t)12*BN*MM + (size_t)row*MM;
    float v[6]; float s = 0.f, s2 = 0.f;
    #pragma unroll
    for (int t = 0; t < 6; ++t) { v[t] = p[lane + t*64]; s += v[t]; s2 += v[t]*v[t]; }
    #pragma unroll
    for (int off = 32; off; off >>= 1) { s += __shfl_xor(s, off); s2 += __shfl_xor(s2, off); }
    float mu  = s * (1.f/MM);
    float inv = rsqrtf(s2 * (1.f/MM) - mu*mu + 1e-5f);
    #pragma unroll
    for (int t = 0; t < 6; ++t) {
        int m = lane + t*64;
        float o = bf2f(af[m]) + (v[t]-mu)*inv * g[m] + beta[m];
        R[(size_t)row*MM + m] = f2bf_hw(fmaxf(o, 0.f));
    }
}

// ---------------- K10: up GEMM (bf16 A, fp32 C + bias) -> d_out ----------------
__global__ __launch_bounds__(256) void k_up(const short* __restrict__ R,
                                            const short* __restrict__ WuT,
                                            const float* __restrict__ bu,
                                            float* __restrict__ Y)
{
    __shared__ char lds[32768];
    const int lg = ((blockIdx.x & 7) * 96) + (blockIdx.x >> 3);
    const int col0 = (lg % 6) * 128;
    const int row0 = (lg / 6) * 128;
    const char* At = (const char*)(R + (size_t)row0*MM);
    const char* Bt = (const char*)(WuT + (size_t)col0*MM);
    f32x4 acc[4][4]; zero_acc(acc);
    gemm_core<0>(At, nullptr, MM, Bt, MM, MM, lds, acc);

    const int tid = threadIdx.x, lane = tid & 63, w = tid >> 6;
    const int wr = w >> 1, wc = w & 1;
    float bj[4];
    #pragma unroll
    for (int j = 0; j < 4; ++j) bj[j] = bu[col0 + wc*64 + j*16 + (lane & 15)];
    #pragma unroll
    for (int i = 0; i < 4; ++i)
        #pragma unroll
        for (int r = 0; r < 4; ++r) {
            int grow = row0 + wr*64 + i*16 + (lane >> 4)*4 + r;
            #pragma unroll
            for (int j = 0; j < 4; ++j) {
                int gcol = col0 + wc*64 + j*16 + (lane & 15);
                Y[(size_t)grow*EE + gcol] = acc[i][j][r] + bj[j];
            }
        }
}

// ---------------- K11: lengths tail ----------------
__global__ void k_len(const int* __restrict__ lengths, float* __restrict__ out)
{
    if (threadIdx.x < BB)
        out[(size_t)BB*NN*EE + threadIdx.x] = (float)lengths[threadIdx.x];
}

extern "C" void kernel_launch(void* const* d_in, const int* in_sizes, int n_in,
                              void* d_out, int out_size, void* d_ws, size_t ws_size,
                              hipStream_t stream)
{
    const float* X    = (const float*)d_in[0];
    const int*   len  = (const int*)  d_in[1];
    const float* Wd   = (const float*)d_in[2];
    const float* bd   = (const float*)d_in[3];
    const float* gd   = (const float*)d_in[4];
    const float* betd = (const float*)d_in[5];
    const float* Wp   = (const float*)d_in[6];
    const float* bp   = (const float*)d_in[7];
    const float* gp   = (const float*)d_in[8];
    const float* betp = (const float*)d_in[9];
    const float* Wu   = (const float*)d_in[10];
    const float* bu   = (const float*)d_in[11];
    const float* Wg   = (const float*)d_in[12];
    const float* bg   = (const float*)d_in[13];
    float* out = (float*)d_out;

    // workspace layout
    float* ws     = (float*)d_ws;
    float* tmp    = ws;                          // 6291456 f
    float* t_raw  = tmp + 6291456;               // 147456 f  (zeroed, atomic acc)
    float* a_raw  = t_raw + 147456;              // 12288 f   (zeroed, atomic acc)
    float* conf   = a_raw + 12288;               // 384 f
    short* down   = (short*)(conf + 384);        // 81788928 sh  [l][b][n][m]
    short* downTb = down   + (size_t)81788928;   // 75497472 sh  [b][m][l][n]
    short* cw     = downTb + (size_t)75497472;   // 100663296 sh [b][n][l*512+k]
    short* R      = cw     + (size_t)100663296;  // 6291456 sh
    short* WdT    = R      + (size_t)6291456;    // 3833856 sh
    short* WpT    = WdT    + (size_t)3833856;    // 147456 sh
    short* WuT    = WpT    + (size_t)147456;     // 294912 sh
    float* msA    = (float*)(WuT + 294912);      // 6291456 f
    float* msB    = msA + 6291456;               // 6291456 f

    // 0) zero the atomic accumulators; weight transposes -> bf16
    k_zero<<<156, 256, 0, stream>>>(t_raw, (147456+12288)/4);
    k_wt<<<dim3(6, 12, 13), 256, 0, stream>>>(Wd, WdT, HH, MM, (size_t)HH*MM, (size_t)HH*MM);
    k_wt<<<dim3(6, 6, 1),   256, 0, stream>>>(Wp, WpT, MM, MM, 0, 0);
    k_wt<<<dim3(12, 6, 1),  256, 0, stream>>>(Wu, WuT, MM, EE, 0, 0);
    // 1) down GEMM (pre-LN bf16), XCD-swizzled 1D grid
    k_down<<<4992, 256, 0, stream>>>(X, WdT, bd, down);
    // 2) LN in place + transposed copy + fused masked-mean raw sums
    k_ln<<<LL*BB*8, 256, 0, stream>>>(down, gd, betd, downTb, len, t_raw, a_raw);
    // 3) conf (1/len^2 folded)
    k_conf<<<BB, 64, 0, stream>>>(a_raw, t_raw, Wg, bg, len, conf);
    // 4) fused S + rowsum + normalize + conf + eye -> cw
    k_srow<<<1536, 512, 0, stream>>>(down, len, conf, cw);
    // 5) split-K merge -> fp32 halves
    k_merge<<<768, 256, 0, stream>>>(cw, downTb, msA, msB);
    // 6) proj (A = msA+msB fused)
    k_proj<<<384, 256, 0, stream>>>(msA, msB, WpT, bp, tmp);
    // 7) residual + LN + relu -> bf16
    k_ln2<<<BN/4, 256, 0, stream>>>(tmp, down, gp, betp, R);
    // 8) up -> out
    k_up<<<768, 256, 0, stream>>>(R, WuT, bu, out);
    // 9) lengths tail
    k_len<<<1, 64, 0, stream>>>(len, out);
}